// Round 1
// baseline (396.565 us; speedup 1.0000x reference)
//
#include <hip/hip_runtime.h>
#include <hip/hip_bf16.h>
#include <cstdint>

#define D_ 1024
#define H_ 16
#define DH_ 64
#define FF_ 4096
#define B_ 2
#define S_ 2048
#define MR_ (B_ * S_)   // 4096 rows

typedef __bf16 bf16x8 __attribute__((ext_vector_type(8)));
typedef float f32x4 __attribute__((ext_vector_type(4)));

// ---- async global->LDS, 16B per lane (linear dest in lane order) ----
__device__ __forceinline__ void g2lds16(const void* g, void* l) {
  __builtin_amdgcn_global_load_lds(
      (__attribute__((address_space(1))) void*)(uintptr_t)g,
      (__attribute__((address_space(3))) void*)(uint32_t)(uintptr_t)l,
      16, 0, 0);
}

// =====================  weight transpose + fp32->bf16  =====================
// W [K,N] fp32 row-major  ->  Wt [N,K] bf16 row-major
__global__ __launch_bounds__(256) void transpose_cvt(
    const float* __restrict__ W, __hip_bfloat16* __restrict__ Wt, int K, int N) {
  __shared__ float t[32][33];
  int bx = blockIdx.x * 32;  // n
  int by = blockIdx.y * 32;  // k
  int tx = threadIdx.x, ty = threadIdx.y;  // (32,8)
#pragma unroll
  for (int i = 0; i < 4; ++i)
    t[ty + 8 * i][tx] = W[(size_t)(by + ty + 8 * i) * N + bx + tx];
  __syncthreads();
#pragma unroll
  for (int i = 0; i < 4; ++i)
    Wt[(size_t)(bx + ty + 8 * i) * K + by + tx] = __float2bfloat16(t[tx][ty + 8 * i]);
}

// ==============  V slice transpose: qkv[b,s, 2D + h*64 + d] -> vT[b,h,d,s]  ==========
__global__ __launch_bounds__(256) void transpose_v(
    const __hip_bfloat16* __restrict__ qkv, __hip_bfloat16* __restrict__ vT) {
  __shared__ __hip_bfloat16 t[32][33];
  int bh = blockIdx.z, b = bh >> 4, h = bh & 15;
  int s0 = blockIdx.x * 32, d0 = blockIdx.y * 32;
  int tx = threadIdx.x, ty = threadIdx.y;
#pragma unroll
  for (int i = 0; i < 4; ++i)
    t[ty + 8 * i][tx] =
        qkv[(size_t)(b * S_ + s0 + ty + 8 * i) * (3 * D_) + 2 * D_ + h * DH_ + d0 + tx];
  __syncthreads();
#pragma unroll
  for (int i = 0; i < 4; ++i)
    vT[(size_t)(bh * DH_ + d0 + ty + 8 * i) * S_ + s0 + tx] = t[tx][ty + 8 * i];
}

// ==========================  LayerNorm (fp32 in, bf16 out)  ========================
__global__ __launch_bounds__(256) void ln_kernel(
    const float* __restrict__ x, const float* __restrict__ g,
    const float* __restrict__ b, __hip_bfloat16* __restrict__ out) {
  int row = blockIdx.x;
  const float4* xr = (const float4*)(x + (size_t)row * D_);
  float4 v = xr[threadIdx.x];
  float s = v.x + v.y + v.z + v.w;
  float ss = v.x * v.x + v.y * v.y + v.z * v.z + v.w * v.w;
#pragma unroll
  for (int m = 1; m < 64; m <<= 1) {
    s += __shfl_xor(s, m);
    ss += __shfl_xor(ss, m);
  }
  __shared__ float rs[4], rss[4];
  int wave = threadIdx.x >> 6, lane = threadIdx.x & 63;
  if (lane == 0) { rs[wave] = s; rss[wave] = ss; }
  __syncthreads();
  s = rs[0] + rs[1] + rs[2] + rs[3];
  ss = rss[0] + rss[1] + rss[2] + rss[3];
  float mean = s * (1.0f / D_);
  float var = ss * (1.0f / D_) - mean * mean;
  float inv = rsqrtf(var + 1e-5f);
  int c = threadIdx.x * 4;
  float4 gv = ((const float4*)g)[threadIdx.x];
  float4 bv = ((const float4*)b)[threadIdx.x];
  __hip_bfloat16* o = out + (size_t)row * D_ + c;
  o[0] = __float2bfloat16((v.x - mean) * inv * gv.x + bv.x);
  o[1] = __float2bfloat16((v.y - mean) * inv * gv.y + bv.y);
  o[2] = __float2bfloat16((v.z - mean) * inv * gv.z + bv.z);
  o[3] = __float2bfloat16((v.w - mean) * inv * gv.w + bv.w);
}

// =====================  GEMM  C[M,N] = A[M,K] * Bt[N,K]^T + bias (+epilogue) ========
// EPI 0: bf16 out + bias;  1: f32 out + bias + resid;  2: bf16 out + bias + gelu
template <int EPI>
__global__ __launch_bounds__(256) void gemm_bt(
    const __hip_bfloat16* __restrict__ A, const __hip_bfloat16* __restrict__ Bt,
    const float* __restrict__ bias, const float* __restrict__ resid,
    void* __restrict__ outp, int M, int N, int K) {
  __shared__ alignas(16) __hip_bfloat16 sA[128 * 64];
  __shared__ alignas(16) __hip_bfloat16 sB[128 * 64];
  const int tid = threadIdx.x;
  const int lane = tid & 63, wave = tid >> 6;
  const int l15 = lane & 15, l4 = lane >> 4;
  const int wr = wave >> 1, wc = wave & 1;  // 2x2 wave grid, 64x64 each
  const int m0 = blockIdx.y * 128, n0 = blockIdx.x * 128;

  f32x4 z = {0.f, 0.f, 0.f, 0.f};
  f32x4 acc[4][4];
#pragma unroll
  for (int i = 0; i < 4; ++i)
#pragma unroll
    for (int j = 0; j < 4; ++j) acc[i][j] = z;

  for (int kt = 0; kt < K; kt += 64) {
#pragma unroll
    for (int it = 0; it < 4; ++it) {
      int idx = it * 256 + tid;
      int r = idx >> 3, c = (idx & 7) * 8;
      g2lds16(A + (size_t)(m0 + r) * K + kt + c, (void*)(sA + idx * 8));
      g2lds16(Bt + (size_t)(n0 + r) * K + kt + c, (void*)(sB + idx * 8));
    }
    __syncthreads();
#pragma unroll
    for (int kk = 0; kk < 2; ++kk) {
      bf16x8 af[4], bfr[4];
#pragma unroll
      for (int f = 0; f < 4; ++f) {
        af[f] = *(const bf16x8*)(sA + (wr * 64 + f * 16 + l15) * 64 + kk * 32 + l4 * 8);
        bfr[f] = *(const bf16x8*)(sB + (wc * 64 + f * 16 + l15) * 64 + kk * 32 + l4 * 8);
      }
#pragma unroll
      for (int mf = 0; mf < 4; ++mf)
#pragma unroll
        for (int nf = 0; nf < 4; ++nf)
          acc[mf][nf] =
              __builtin_amdgcn_mfma_f32_16x16x32_bf16(af[mf], bfr[nf], acc[mf][nf], 0, 0, 0);
    }
    __syncthreads();
  }

#pragma unroll
  for (int mf = 0; mf < 4; ++mf) {
#pragma unroll
    for (int nf = 0; nf < 4; ++nf) {
      int col = n0 + wc * 64 + nf * 16 + l15;
      float bv = bias[col];
#pragma unroll
      for (int j = 0; j < 4; ++j) {
        int row = m0 + wr * 64 + mf * 16 + l4 * 4 + j;
        size_t o = (size_t)row * N + col;
        float v = acc[mf][nf][j] + bv;
        if (EPI == 0) {
          ((__hip_bfloat16*)outp)[o] = __float2bfloat16(v);
        } else if (EPI == 1) {
          ((float*)outp)[o] = v + resid[o];
        } else {
          float a = 0.7978845608028654f * (v + 0.044715f * v * v * v);
          a = fminf(fmaxf(a, -15.f), 15.f);
          float e = __expf(2.f * a);
          float th = (e - 1.f) / (e + 1.f);
          ((__hip_bfloat16*)outp)[o] = __float2bfloat16(0.5f * v * (1.f + th));
        }
      }
    }
  }
}

// ===============================  Flash attention  =================================
// grid (S/64, B*H). 4 waves, each owns 16 q-rows. KB=64 chunks.
__global__ __launch_bounds__(256) void attn_kernel(
    const __hip_bfloat16* __restrict__ qkv, const __hip_bfloat16* __restrict__ vT,
    __hip_bfloat16* __restrict__ out) {
  __shared__ alignas(16) __hip_bfloat16 sK[64 * 64];   // [kv][dh]
  __shared__ alignas(16) __hip_bfloat16 sV[64 * 64];   // [dh][kv]
  __shared__ alignas(16) __hip_bfloat16 sP[4][16 * 80];  // per-wave [q][kv(pad 80)]
  const int tid = threadIdx.x, lane = tid & 63, wave = tid >> 6;
  const int l15 = lane & 15, l4 = lane >> 4;
  const int bh = blockIdx.y, b = bh >> 4, h = bh & 15;
  const int q0 = blockIdx.x * 64;

  const int qr = q0 + wave * 16 + l15;
  const size_t qbase = ((size_t)(b * S_ + qr)) * (3 * D_) + h * DH_;
  bf16x8 qf[2];
  qf[0] = *(const bf16x8*)(qkv + qbase + l4 * 8);
  qf[1] = *(const bf16x8*)(qkv + qbase + 32 + l4 * 8);

  f32x4 z = {0.f, 0.f, 0.f, 0.f};
  f32x4 acc[4];
#pragma unroll
  for (int i = 0; i < 4; ++i) acc[i] = z;
  float mrun[4] = {-1e30f, -1e30f, -1e30f, -1e30f};
  float lrun[4] = {0.f, 0.f, 0.f, 0.f};

  const size_t kbase = (size_t)b * S_ * (3 * D_) + D_ + h * DH_;
  const size_t vbase = (size_t)bh * DH_ * S_;

  for (int kv0 = 0; kv0 < S_; kv0 += 64) {
#pragma unroll
    for (int it = 0; it < 2; ++it) {
      int idx = it * 256 + tid;
      int r = idx >> 3, c = (idx & 7) * 8;
      g2lds16(qkv + kbase + (size_t)(kv0 + r) * (3 * D_) + c, (void*)(sK + idx * 8));
      g2lds16(vT + vbase + (size_t)r * S_ + kv0 + c, (void*)(sV + idx * 8));
    }
    __syncthreads();

    f32x4 sf[4];
#pragma unroll
    for (int i = 0; i < 4; ++i) sf[i] = z;
#pragma unroll
    for (int nf = 0; nf < 4; ++nf)
#pragma unroll
      for (int ks = 0; ks < 2; ++ks) {
        bf16x8 kf = *(const bf16x8*)(sK + (nf * 16 + l15) * 64 + ks * 32 + l4 * 8);
        sf[nf] = __builtin_amdgcn_mfma_f32_16x16x32_bf16(qf[ks], kf, sf[nf], 0, 0, 0);
      }

    // online softmax (rows: q = l4*4 + j, cols: kv = nf*16 + l15)
#pragma unroll
    for (int j = 0; j < 4; ++j) {
      float mx = fmaxf(fmaxf(sf[0][j], sf[1][j]), fmaxf(sf[2][j], sf[3][j])) * 0.125f;
#pragma unroll
      for (int sh = 1; sh < 16; sh <<= 1) mx = fmaxf(mx, __shfl_xor(mx, sh));
      float mnew = fmaxf(mrun[j], mx);
      float corr = __expf(mrun[j] - mnew);
      mrun[j] = mnew;
      float ps = 0.f;
#pragma unroll
      for (int nf = 0; nf < 4; ++nf) {
        float p = __expf(sf[nf][j] * 0.125f - mnew);
        ps += p;
        sP[wave][(l4 * 4 + j) * 80 + nf * 16 + l15] = __float2bfloat16(p);
      }
#pragma unroll
      for (int sh = 1; sh < 16; sh <<= 1) ps += __shfl_xor(ps, sh);
      lrun[j] = lrun[j] * corr + ps;
#pragma unroll
      for (int nf = 0; nf < 4; ++nf) acc[nf][j] *= corr;
    }

    // PV: A = P[q=l15][kv], B = V[kv][dh] read via vT LDS
#pragma unroll
    for (int ks = 0; ks < 2; ++ks) {
      bf16x8 pf = *(const bf16x8*)(&sP[wave][l15 * 80 + ks * 32 + l4 * 8]);
#pragma unroll
      for (int nf = 0; nf < 4; ++nf) {
        bf16x8 vf = *(const bf16x8*)(sV + (nf * 16 + l15) * 64 + ks * 32 + l4 * 8);
        acc[nf] = __builtin_amdgcn_mfma_f32_16x16x32_bf16(pf, vf, acc[nf], 0, 0, 0);
      }
    }
    __syncthreads();
  }

#pragma unroll
  for (int j = 0; j < 4; ++j) {
    float inv = 1.0f / lrun[j];
    int row = q0 + wave * 16 + l4 * 4 + j;
    size_t o = ((size_t)(b * S_ + row)) * D_ + h * DH_;
#pragma unroll
    for (int nf = 0; nf < 4; ++nf)
      out[o + nf * 16 + l15] = __float2bfloat16(acc[nf][j] * inv);
  }
}

// ====================================================================================
extern "C" void kernel_launch(void* const* d_in, const int* in_sizes, int n_in,
                              void* d_out, int out_size, void* d_ws, size_t ws_size,
                              hipStream_t stream) {
  const float* x = (const float*)d_in[0];
  const float* ln1_g = (const float*)d_in[1];
  const float* ln1_b = (const float*)d_in[2];
  const float* Wqkv = (const float*)d_in[3];
  const float* bqkv = (const float*)d_in[4];
  const float* Wo = (const float*)d_in[5];
  const float* bo = (const float*)d_in[6];
  const float* ln2_g = (const float*)d_in[7];
  const float* ln2_b = (const float*)d_in[8];
  const float* W1 = (const float*)d_in[9];
  const float* b1 = (const float*)d_in[10];
  const float* W2 = (const float*)d_in[11];
  const float* b2 = (const float*)d_in[12];
  float* out = (float*)d_out;

  char* ws = (char*)d_ws;
  size_t off = 0;
  auto alloc = [&](size_t bytes) {
    void* p = ws + off;
    off += (bytes + 255) & ~(size_t)255;
    return p;
  };
  __hip_bfloat16* WqkvT = (__hip_bfloat16*)alloc((size_t)3 * D_ * D_ * 2);
  __hip_bfloat16* WoT = (__hip_bfloat16*)alloc((size_t)D_ * D_ * 2);
  __hip_bfloat16* W1T = (__hip_bfloat16*)alloc((size_t)FF_ * D_ * 2);
  __hip_bfloat16* W2T = (__hip_bfloat16*)alloc((size_t)D_ * FF_ * 2);
  __hip_bfloat16* h = (__hip_bfloat16*)alloc((size_t)MR_ * D_ * 2);
  __hip_bfloat16* qkv = (__hip_bfloat16*)alloc((size_t)MR_ * FF_ * 2);  // shared w/ ff
  __hip_bfloat16* ff = qkv;
  __hip_bfloat16* vT = (__hip_bfloat16*)alloc((size_t)B_ * H_ * DH_ * S_ * 2);
  __hip_bfloat16* attn_out = (__hip_bfloat16*)alloc((size_t)MR_ * D_ * 2);

  dim3 tb(32, 8);
  // 1. weight prep
  transpose_cvt<<<dim3(3 * D_ / 32, D_ / 32), tb, 0, stream>>>(Wqkv, WqkvT, D_, 3 * D_);
  transpose_cvt<<<dim3(D_ / 32, D_ / 32), tb, 0, stream>>>(Wo, WoT, D_, D_);
  transpose_cvt<<<dim3(FF_ / 32, D_ / 32), tb, 0, stream>>>(W1, W1T, D_, FF_);
  transpose_cvt<<<dim3(D_ / 32, FF_ / 32), tb, 0, stream>>>(W2, W2T, FF_, D_);
  // 2. LN1
  ln_kernel<<<MR_, 256, 0, stream>>>(x, ln1_g, ln1_b, h);
  // 3. QKV gemm
  gemm_bt<0><<<dim3(3 * D_ / 128, MR_ / 128), 256, 0, stream>>>(
      h, WqkvT, bqkv, nullptr, qkv, MR_, 3 * D_, D_);
  // 4. V transpose
  transpose_v<<<dim3(S_ / 32, DH_ / 32, B_ * H_), tb, 0, stream>>>(qkv, vT);
  // 5. attention
  attn_kernel<<<dim3(S_ / 64, B_ * H_), 256, 0, stream>>>(qkv, vT, attn_out);
  // 6. Wo gemm + residual -> d_out (x2, fp32)
  gemm_bt<1><<<dim3(D_ / 128, MR_ / 128), 256, 0, stream>>>(
      attn_out, WoT, bo, x, out, MR_, D_, D_);
  // 7. LN2 (reuse h)
  ln_kernel<<<MR_, 256, 0, stream>>>(out, ln2_g, ln2_b, h);
  // 8. W1 gemm + gelu
  gemm_bt<2><<<dim3(FF_ / 128, MR_ / 128), 256, 0, stream>>>(
      h, W1T, b1, nullptr, ff, MR_, FF_, D_);
  // 9. W2 gemm + residual(d_out) -> d_out
  gemm_bt<1><<<dim3(D_ / 128, MR_ / 128), 256, 0, stream>>>(
      ff, W2T, b2, out, out, MR_, D_, FF_);
}

// Round 2
// 354.167 us; speedup vs baseline: 1.1197x; 1.1197x over previous
//
#include <hip/hip_runtime.h>
#include <hip/hip_bf16.h>
#include <cstdint>

#define D_ 1024
#define H_ 16
#define DH_ 64
#define FF_ 4096
#define B_ 2
#define S_ 2048
#define MR_ (B_ * S_)   // 4096 rows

typedef __bf16 bf16x8 __attribute__((ext_vector_type(8)));
typedef float f32x4 __attribute__((ext_vector_type(4)));

// ---- async global->LDS, 16B per lane (linear dest in lane order) ----
__device__ __forceinline__ void g2lds16(const void* g, void* l) {
  __builtin_amdgcn_global_load_lds(
      (__attribute__((address_space(1))) void*)(uintptr_t)g,
      (__attribute__((address_space(3))) void*)(uint32_t)(uintptr_t)l,
      16, 0, 0);
}

// =====================  weight transpose + fp32->bf16  =====================
// W [K,N] fp32 row-major  ->  Wt [N,K] bf16 row-major
__global__ __launch_bounds__(256) void transpose_cvt(
    const float* __restrict__ W, __hip_bfloat16* __restrict__ Wt, int K, int N) {
  __shared__ float t[32][33];
  int bx = blockIdx.x * 32;  // n
  int by = blockIdx.y * 32;  // k
  int tx = threadIdx.x, ty = threadIdx.y;  // (32,8)
#pragma unroll
  for (int i = 0; i < 4; ++i)
    t[ty + 8 * i][tx] = W[(size_t)(by + ty + 8 * i) * N + bx + tx];
  __syncthreads();
#pragma unroll
  for (int i = 0; i < 4; ++i)
    Wt[(size_t)(bx + ty + 8 * i) * K + by + tx] = __float2bfloat16(t[tx][ty + 8 * i]);
}

// ==============  V slice transpose: qkv[b,s, 2D + h*64 + d] -> vT[b,h,d,s]  ==========
__global__ __launch_bounds__(256) void transpose_v(
    const __hip_bfloat16* __restrict__ qkv, __hip_bfloat16* __restrict__ vT) {
  __shared__ __hip_bfloat16 t[32][33];
  int bh = blockIdx.z, b = bh >> 4, h = bh & 15;
  int s0 = blockIdx.x * 32, d0 = blockIdx.y * 32;
  int tx = threadIdx.x, ty = threadIdx.y;
#pragma unroll
  for (int i = 0; i < 4; ++i)
    t[ty + 8 * i][tx] =
        qkv[(size_t)(b * S_ + s0 + ty + 8 * i) * (3 * D_) + 2 * D_ + h * DH_ + d0 + tx];
  __syncthreads();
#pragma unroll
  for (int i = 0; i < 4; ++i)
    vT[(size_t)(bh * DH_ + d0 + ty + 8 * i) * S_ + s0 + tx] = t[tx][ty + 8 * i];
}

// ==========================  LayerNorm (fp32 in, bf16 out)  ========================
__global__ __launch_bounds__(256) void ln_kernel(
    const float* __restrict__ x, const float* __restrict__ g,
    const float* __restrict__ b, __hip_bfloat16* __restrict__ out) {
  int row = blockIdx.x;
  const float4* xr = (const float4*)(x + (size_t)row * D_);
  float4 v = xr[threadIdx.x];
  float s = v.x + v.y + v.z + v.w;
  float ss = v.x * v.x + v.y * v.y + v.z * v.z + v.w * v.w;
#pragma unroll
  for (int m = 1; m < 64; m <<= 1) {
    s += __shfl_xor(s, m);
    ss += __shfl_xor(ss, m);
  }
  __shared__ float rs[4], rss[4];
  int wave = threadIdx.x >> 6, lane = threadIdx.x & 63;
  if (lane == 0) { rs[wave] = s; rss[wave] = ss; }
  __syncthreads();
  s = rs[0] + rs[1] + rs[2] + rs[3];
  ss = rss[0] + rss[1] + rss[2] + rss[3];
  float mean = s * (1.0f / D_);
  float var = ss * (1.0f / D_) - mean * mean;
  float inv = rsqrtf(var + 1e-5f);
  int c = threadIdx.x * 4;
  float4 gv = ((const float4*)g)[threadIdx.x];
  float4 bv = ((const float4*)b)[threadIdx.x];
  __hip_bfloat16* o = out + (size_t)row * D_ + c;
  o[0] = __float2bfloat16((v.x - mean) * inv * gv.x + bv.x);
  o[1] = __float2bfloat16((v.y - mean) * inv * gv.y + bv.y);
  o[2] = __float2bfloat16((v.z - mean) * inv * gv.z + bv.z);
  o[3] = __float2bfloat16((v.w - mean) * inv * gv.w + bv.w);
}

// =====================  GEMM  C[M,N] = A[M,K] * Bt[N,K]^T + bias (+epilogue) ========
// EPI 0: bf16 out + bias;  1: f32 out + bias + resid;  2: bf16 out + bias + gelu
template <int EPI>
__global__ __launch_bounds__(256) void gemm_bt(
    const __hip_bfloat16* __restrict__ A, const __hip_bfloat16* __restrict__ Bt,
    const float* __restrict__ bias, const float* __restrict__ resid,
    void* __restrict__ outp, int M, int N, int K) {
  __shared__ alignas(16) __hip_bfloat16 sA[128 * 64];
  __shared__ alignas(16) __hip_bfloat16 sB[128 * 64];
  const int tid = threadIdx.x;
  const int lane = tid & 63, wave = tid >> 6;
  const int l15 = lane & 15, l4 = lane >> 4;
  const int wr = wave >> 1, wc = wave & 1;  // 2x2 wave grid, 64x64 each
  const int m0 = blockIdx.y * 128, n0 = blockIdx.x * 128;

  f32x4 z = {0.f, 0.f, 0.f, 0.f};
  f32x4 acc[4][4];
#pragma unroll
  for (int i = 0; i < 4; ++i)
#pragma unroll
    for (int j = 0; j < 4; ++j) acc[i][j] = z;

  for (int kt = 0; kt < K; kt += 64) {
#pragma unroll
    for (int it = 0; it < 4; ++it) {
      int idx = it * 256 + tid;
      int r = idx >> 3, c = (idx & 7) * 8;
      g2lds16(A + (size_t)(m0 + r) * K + kt + c, (void*)(sA + idx * 8));
      g2lds16(Bt + (size_t)(n0 + r) * K + kt + c, (void*)(sB + idx * 8));
    }
    __syncthreads();
#pragma unroll
    for (int kk = 0; kk < 2; ++kk) {
      bf16x8 af[4], bfr[4];
#pragma unroll
      for (int f = 0; f < 4; ++f) {
        af[f] = *(const bf16x8*)(sA + (wr * 64 + f * 16 + l15) * 64 + kk * 32 + l4 * 8);
        bfr[f] = *(const bf16x8*)(sB + (wc * 64 + f * 16 + l15) * 64 + kk * 32 + l4 * 8);
      }
#pragma unroll
      for (int mf = 0; mf < 4; ++mf)
#pragma unroll
        for (int nf = 0; nf < 4; ++nf)
          acc[mf][nf] =
              __builtin_amdgcn_mfma_f32_16x16x32_bf16(af[mf], bfr[nf], acc[mf][nf], 0, 0, 0);
    }
    __syncthreads();
  }

#pragma unroll
  for (int mf = 0; mf < 4; ++mf) {
#pragma unroll
    for (int nf = 0; nf < 4; ++nf) {
      int col = n0 + wc * 64 + nf * 16 + l15;
      float bv = bias[col];
#pragma unroll
      for (int j = 0; j < 4; ++j) {
        int row = m0 + wr * 64 + mf * 16 + l4 * 4 + j;
        size_t o = (size_t)row * N + col;
        float v = acc[mf][nf][j] + bv;
        if (EPI == 0) {
          ((__hip_bfloat16*)outp)[o] = __float2bfloat16(v);
        } else if (EPI == 1) {
          ((float*)outp)[o] = v + resid[o];
        } else {
          float a = 0.7978845608028654f * (v + 0.044715f * v * v * v);
          a = fminf(fmaxf(a, -15.f), 15.f);
          float e = __expf(2.f * a);
          float th = (e - 1.f) / (e + 1.f);
          ((__hip_bfloat16*)outp)[o] = __float2bfloat16(0.5f * v * (1.f + th));
        }
      }
    }
  }
}

// ===============================  Flash attention  =================================
// grid (S/128, B*H). 4 waves, each owns 32 q-rows (2 x 16-row fragments). KB=64.
// K/V double-buffered in LDS with XOR bank swizzle (both-sides: pre-swizzled global
// source + swizzled ds_read). One barrier per tile.
__global__ __launch_bounds__(256) void attn_kernel(
    const __hip_bfloat16* __restrict__ qkv, const __hip_bfloat16* __restrict__ vT,
    __hip_bfloat16* __restrict__ out) {
  __shared__ alignas(16) __hip_bfloat16 sK[2][64 * 64];   // [kv][dh], swizzled
  __shared__ alignas(16) __hip_bfloat16 sV[2][64 * 64];   // [dh][kv], swizzled
  __shared__ alignas(16) __hip_bfloat16 sP[4][32 * 72];   // per-wave [q][kv] stride 72
  const int tid = threadIdx.x, lane = tid & 63, wave = tid >> 6;
  const int l15 = lane & 15, l4 = lane >> 4;
  const int bh = blockIdx.y, b = bh >> 4, h = bh & 15;
  const int q0 = blockIdx.x * 128;

  // Q fragments: 2 x 16 q-rows per wave, held in registers
  bf16x8 qf[2][2];
#pragma unroll
  for (int mf = 0; mf < 2; ++mf) {
    int qr = q0 + wave * 32 + mf * 16 + l15;
    const size_t qb = ((size_t)(b * S_ + qr)) * (3 * D_) + h * DH_;
    qf[mf][0] = *(const bf16x8*)(qkv + qb + l4 * 8);
    qf[mf][1] = *(const bf16x8*)(qkv + qb + 32 + l4 * 8);
  }

  f32x4 z = {0.f, 0.f, 0.f, 0.f};
  f32x4 acc[2][4];
#pragma unroll
  for (int mf = 0; mf < 2; ++mf)
#pragma unroll
    for (int nf = 0; nf < 4; ++nf) acc[mf][nf] = z;
  float mrun2[2][4], lrun[2][4];
#pragma unroll
  for (int mf = 0; mf < 2; ++mf)
#pragma unroll
    for (int j = 0; j < 4; ++j) { mrun2[mf][j] = -1e30f; lrun[mf][j] = 0.f; }

  const __hip_bfloat16* kg = qkv + (size_t)b * S_ * (3 * D_) + D_ + h * DH_;
  const __hip_bfloat16* vg = vT + (size_t)bh * DH_ * S_;

  auto stage = [&](int bu, int kv0) {
#pragma unroll
    for (int it = 0; it < 2; ++it) {
      int idx = it * 256 + tid;          // 0..511
      int r = idx >> 3;                  // 0..63
      int c = (idx & 7) * 8;             // 0..56
      int cs = c ^ ((r & 7) << 3);       // inverse-swizzled source column
      g2lds16(kg + (size_t)(kv0 + r) * (3 * D_) + cs, (void*)(&sK[bu][idx * 8]));
      g2lds16(vg + (size_t)r * S_ + kv0 + cs, (void*)(&sV[bu][idx * 8]));
    }
  };

  stage(0, 0);
  const float k2 = 0.125f * 1.44269504f;  // scale * log2(e)
  const int NT = S_ / 64;

  for (int t = 0; t < NT; ++t) {
    const int cur = t & 1;
    __syncthreads();                       // drains our stage loads; guards buf reuse
    if (t + 1 < NT) stage(cur ^ 1, (t + 1) * 64);

    // ---- QK^T ----
    f32x4 sf[2][4];
#pragma unroll
    for (int mf = 0; mf < 2; ++mf)
#pragma unroll
      for (int nf = 0; nf < 4; ++nf) sf[mf][nf] = z;
    __builtin_amdgcn_s_setprio(1);
#pragma unroll
    for (int ks = 0; ks < 2; ++ks) {
      int colsw = (ks * 32 + l4 * 8) ^ ((l15 & 7) << 3);
#pragma unroll
      for (int nf = 0; nf < 4; ++nf) {
        bf16x8 kf = *(const bf16x8*)(&sK[cur][(nf * 16 + l15) * 64 + colsw]);
        sf[0][nf] = __builtin_amdgcn_mfma_f32_16x16x32_bf16(qf[0][ks], kf, sf[0][nf], 0, 0, 0);
        sf[1][nf] = __builtin_amdgcn_mfma_f32_16x16x32_bf16(qf[1][ks], kf, sf[1][nf], 0, 0, 0);
      }
    }
    __builtin_amdgcn_s_setprio(0);

    // ---- online softmax (log2 domain; per-lane partial row sums) ----
    float mx2[2][4];
    float need = -1.f;
#pragma unroll
    for (int mf = 0; mf < 2; ++mf)
#pragma unroll
      for (int j = 0; j < 4; ++j) {
        float m_ = fmaxf(fmaxf(sf[mf][0][j], sf[mf][1][j]),
                         fmaxf(sf[mf][2][j], sf[mf][3][j])) * k2;
#pragma unroll
        for (int sh = 1; sh < 16; sh <<= 1) m_ = fmaxf(m_, __shfl_xor(m_, sh));
        mx2[mf][j] = m_;
        need = fmaxf(need, m_ - mrun2[mf][j] - 11.0f);
      }
    if (!__all(need <= 0.f)) {   // rescale only when some row's max grew past THR
#pragma unroll
      for (int mf = 0; mf < 2; ++mf)
#pragma unroll
        for (int j = 0; j < 4; ++j) {
          float mn = fmaxf(mrun2[mf][j], mx2[mf][j]);
          float corr = exp2f(mrun2[mf][j] - mn);
          mrun2[mf][j] = mn;
          lrun[mf][j] *= corr;
#pragma unroll
          for (int nf = 0; nf < 4; ++nf) acc[mf][nf][j] *= corr;
        }
    }
#pragma unroll
    for (int mf = 0; mf < 2; ++mf)
#pragma unroll
      for (int j = 0; j < 4; ++j) {
        float ps = 0.f;
#pragma unroll
        for (int nf = 0; nf < 4; ++nf) {
          float p = exp2f(sf[mf][nf][j] * k2 - mrun2[mf][j]);
          ps += p;
          sP[wave][(mf * 16 + l4 * 4 + j) * 72 + nf * 16 + l15] = __float2bfloat16(p);
        }
        lrun[mf][j] += ps;   // per-lane partial; reduced once in epilogue
      }

    // ---- PV ----
    __builtin_amdgcn_s_setprio(1);
#pragma unroll
    for (int ks = 0; ks < 2; ++ks) {
      int colsw = (ks * 32 + l4 * 8) ^ ((l15 & 7) << 3);
      bf16x8 pf0 = *(const bf16x8*)(&sP[wave][l15 * 72 + ks * 32 + l4 * 8]);
      bf16x8 pf1 = *(const bf16x8*)(&sP[wave][(16 + l15) * 72 + ks * 32 + l4 * 8]);
#pragma unroll
      for (int nf = 0; nf < 4; ++nf) {
        bf16x8 vf = *(const bf16x8*)(&sV[cur][(nf * 16 + l15) * 64 + colsw]);
        acc[0][nf] = __builtin_amdgcn_mfma_f32_16x16x32_bf16(pf0, vf, acc[0][nf], 0, 0, 0);
        acc[1][nf] = __builtin_amdgcn_mfma_f32_16x16x32_bf16(pf1, vf, acc[1][nf], 0, 0, 0);
      }
    }
    __builtin_amdgcn_s_setprio(0);
  }

  // ---- epilogue: finish row-sum reduce, normalize, store ----
#pragma unroll
  for (int mf = 0; mf < 2; ++mf)
#pragma unroll
    for (int j = 0; j < 4; ++j) {
      float l_ = lrun[mf][j];
#pragma unroll
      for (int sh = 1; sh < 16; sh <<= 1) l_ += __shfl_xor(l_, sh);
      float inv = 1.0f / l_;
      int row = q0 + wave * 32 + mf * 16 + l4 * 4 + j;
      size_t o = ((size_t)(b * S_ + row)) * D_ + h * DH_;
#pragma unroll
      for (int nf = 0; nf < 4; ++nf)
        out[o + nf * 16 + l15] = __float2bfloat16(acc[mf][nf][j] * inv);
    }
}

// ====================================================================================
extern "C" void kernel_launch(void* const* d_in, const int* in_sizes, int n_in,
                              void* d_out, int out_size, void* d_ws, size_t ws_size,
                              hipStream_t stream) {
  const float* x = (const float*)d_in[0];
  const float* ln1_g = (const float*)d_in[1];
  const float* ln1_b = (const float*)d_in[2];
  const float* Wqkv = (const float*)d_in[3];
  const float* bqkv = (const float*)d_in[4];
  const float* Wo = (const float*)d_in[5];
  const float* bo = (const float*)d_in[6];
  const float* ln2_g = (const float*)d_in[7];
  const float* ln2_b = (const float*)d_in[8];
  const float* W1 = (const float*)d_in[9];
  const float* b1 = (const float*)d_in[10];
  const float* W2 = (const float*)d_in[11];
  const float* b2 = (const float*)d_in[12];
  float* out = (float*)d_out;

  char* ws = (char*)d_ws;
  size_t off = 0;
  auto alloc = [&](size_t bytes) {
    void* p = ws + off;
    off += (bytes + 255) & ~(size_t)255;
    return p;
  };
  __hip_bfloat16* WqkvT = (__hip_bfloat16*)alloc((size_t)3 * D_ * D_ * 2);
  __hip_bfloat16* WoT = (__hip_bfloat16*)alloc((size_t)D_ * D_ * 2);
  __hip_bfloat16* W1T = (__hip_bfloat16*)alloc((size_t)FF_ * D_ * 2);
  __hip_bfloat16* W2T = (__hip_bfloat16*)alloc((size_t)D_ * FF_ * 2);
  __hip_bfloat16* h = (__hip_bfloat16*)alloc((size_t)MR_ * D_ * 2);
  __hip_bfloat16* qkv = (__hip_bfloat16*)alloc((size_t)MR_ * FF_ * 2);  // shared w/ ff
  __hip_bfloat16* ff = qkv;
  __hip_bfloat16* vT = (__hip_bfloat16*)alloc((size_t)B_ * H_ * DH_ * S_ * 2);
  __hip_bfloat16* attn_out = (__hip_bfloat16*)alloc((size_t)MR_ * D_ * 2);

  dim3 tb(32, 8);
  // 1. weight prep
  transpose_cvt<<<dim3(3 * D_ / 32, D_ / 32), tb, 0, stream>>>(Wqkv, WqkvT, D_, 3 * D_);
  transpose_cvt<<<dim3(D_ / 32, D_ / 32), tb, 0, stream>>>(Wo, WoT, D_, D_);
  transpose_cvt<<<dim3(FF_ / 32, D_ / 32), tb, 0, stream>>>(W1, W1T, D_, FF_);
  transpose_cvt<<<dim3(D_ / 32, FF_ / 32), tb, 0, stream>>>(W2, W2T, FF_, D_);
  // 2. LN1
  ln_kernel<<<MR_, 256, 0, stream>>>(x, ln1_g, ln1_b, h);
  // 3. QKV gemm
  gemm_bt<0><<<dim3(3 * D_ / 128, MR_ / 128), 256, 0, stream>>>(
      h, WqkvT, bqkv, nullptr, qkv, MR_, 3 * D_, D_);
  // 4. V transpose
  transpose_v<<<dim3(S_ / 32, DH_ / 32, B_ * H_), tb, 0, stream>>>(qkv, vT);
  // 5. attention
  attn_kernel<<<dim3(S_ / 128, B_ * H_), 256, 0, stream>>>(qkv, vT, attn_out);
  // 6. Wo gemm + residual -> d_out (x2, fp32)
  gemm_bt<1><<<dim3(D_ / 128, MR_ / 128), 256, 0, stream>>>(
      attn_out, WoT, bo, x, out, MR_, D_, D_);
  // 7. LN2 (reuse h)
  ln_kernel<<<MR_, 256, 0, stream>>>(out, ln2_g, ln2_b, h);
  // 8. W1 gemm + gelu
  gemm_bt<2><<<dim3(FF_ / 128, MR_ / 128), 256, 0, stream>>>(
      h, W1T, b1, nullptr, ff, MR_, FF_, D_);
  // 9. W2 gemm + residual(d_out) -> d_out
  gemm_bt<1><<<dim3(D_ / 128, MR_ / 128), 256, 0, stream>>>(
      ff, W2T, b2, out, out, MR_, D_, FF_);
}

// Round 3
// 317.295 us; speedup vs baseline: 1.2498x; 1.1162x over previous
//
#include <hip/hip_runtime.h>
#include <hip/hip_bf16.h>
#include <cstdint>

#define D_ 1024
#define H_ 16
#define DH_ 64
#define FF_ 4096
#define B_ 2
#define S_ 2048
#define MR_ (B_ * S_)   // 4096 rows

typedef __bf16 bf16x8 __attribute__((ext_vector_type(8)));
typedef float f32x4 __attribute__((ext_vector_type(4)));

// ---- async global->LDS, 16B per lane (linear dest in lane order) ----
__device__ __forceinline__ void g2lds16(const void* g, void* l) {
  __builtin_amdgcn_global_load_lds(
      (__attribute__((address_space(1))) void*)(uintptr_t)g,
      (__attribute__((address_space(3))) void*)(uint32_t)(uintptr_t)l,
      16, 0, 0);
}

// =====================  weight transpose + fp32->bf16  =====================
// W [K,N] fp32 row-major  ->  Wt [N,K] bf16 row-major
__global__ __launch_bounds__(256) void transpose_cvt(
    const float* __restrict__ W, __hip_bfloat16* __restrict__ Wt, int K, int N) {
  __shared__ float t[32][33];
  int bx = blockIdx.x * 32;  // n
  int by = blockIdx.y * 32;  // k
  int tx = threadIdx.x, ty = threadIdx.y;  // (32,8)
#pragma unroll
  for (int i = 0; i < 4; ++i)
    t[ty + 8 * i][tx] = W[(size_t)(by + ty + 8 * i) * N + bx + tx];
  __syncthreads();
#pragma unroll
  for (int i = 0; i < 4; ++i)
    Wt[(size_t)(bx + ty + 8 * i) * K + by + tx] = __float2bfloat16(t[tx][ty + 8 * i]);
}

// ==============  V slice transpose: qkv[b,s, 2D + h*64 + d] -> vT[b,h,d,s]  ==========
__global__ __launch_bounds__(256) void transpose_v(
    const __hip_bfloat16* __restrict__ qkv, __hip_bfloat16* __restrict__ vT) {
  __shared__ __hip_bfloat16 t[32][33];
  int bh = blockIdx.z, b = bh >> 4, h = bh & 15;
  int s0 = blockIdx.x * 32, d0 = blockIdx.y * 32;
  int tx = threadIdx.x, ty = threadIdx.y;
#pragma unroll
  for (int i = 0; i < 4; ++i)
    t[ty + 8 * i][tx] =
        qkv[(size_t)(b * S_ + s0 + ty + 8 * i) * (3 * D_) + 2 * D_ + h * DH_ + d0 + tx];
  __syncthreads();
#pragma unroll
  for (int i = 0; i < 4; ++i)
    vT[(size_t)(bh * DH_ + d0 + ty + 8 * i) * S_ + s0 + tx] = t[tx][ty + 8 * i];
}

// ==========================  LayerNorm (fp32 in, bf16 out)  ========================
__global__ __launch_bounds__(256) void ln_kernel(
    const float* __restrict__ x, const float* __restrict__ g,
    const float* __restrict__ b, __hip_bfloat16* __restrict__ out) {
  int row = blockIdx.x;
  const float4* xr = (const float4*)(x + (size_t)row * D_);
  float4 v = xr[threadIdx.x];
  float s = v.x + v.y + v.z + v.w;
  float ss = v.x * v.x + v.y * v.y + v.z * v.z + v.w * v.w;
#pragma unroll
  for (int m = 1; m < 64; m <<= 1) {
    s += __shfl_xor(s, m);
    ss += __shfl_xor(ss, m);
  }
  __shared__ float rs[4], rss[4];
  int wave = threadIdx.x >> 6, lane = threadIdx.x & 63;
  if (lane == 0) { rs[wave] = s; rss[wave] = ss; }
  __syncthreads();
  s = rs[0] + rs[1] + rs[2] + rs[3];
  ss = rss[0] + rss[1] + rss[2] + rss[3];
  float mean = s * (1.0f / D_);
  float var = ss * (1.0f / D_) - mean * mean;
  float inv = rsqrtf(var + 1e-5f);
  int c = threadIdx.x * 4;
  float4 gv = ((const float4*)g)[threadIdx.x];
  float4 bv = ((const float4*)b)[threadIdx.x];
  __hip_bfloat16* o = out + (size_t)row * D_ + c;
  o[0] = __float2bfloat16((v.x - mean) * inv * gv.x + bv.x);
  o[1] = __float2bfloat16((v.y - mean) * inv * gv.y + bv.y);
  o[2] = __float2bfloat16((v.z - mean) * inv * gv.z + bv.z);
  o[3] = __float2bfloat16((v.w - mean) * inv * gv.w + bv.w);
}

// =====================  GEMM  C[M,N] = A[M,K] * Bt[N,K]^T + bias (+epilogue) ========
// EPI 0: bf16 out + bias;  1: f32 out + bias + resid;  2: bf16 out + bias + gelu
// Tile BM x BN, 4 waves arranged WM x WN (WM*WN==4). BK=64 fixed.
template <int EPI, int BM, int BN, int WM, int WN>
__global__ __launch_bounds__(256) void gemm_bt(
    const __hip_bfloat16* __restrict__ A, const __hip_bfloat16* __restrict__ Bt,
    const float* __restrict__ bias, const float* __restrict__ resid,
    void* __restrict__ outp, int M, int N, int K) {
  constexpr int MF = BM / (WM * 16);
  constexpr int NF = BN / (WN * 16);
  __shared__ alignas(16) __hip_bfloat16 sA[BM * 64];
  __shared__ alignas(16) __hip_bfloat16 sB[BN * 64];
  const int tid = threadIdx.x;
  const int lane = tid & 63, wave = tid >> 6;
  const int l15 = lane & 15, l4 = lane >> 4;
  const int wr = wave / WN, wc = wave % WN;
  const int m0 = blockIdx.y * BM, n0 = blockIdx.x * BN;

  f32x4 z = {0.f, 0.f, 0.f, 0.f};
  f32x4 acc[MF][NF];
#pragma unroll
  for (int i = 0; i < MF; ++i)
#pragma unroll
    for (int j = 0; j < NF; ++j) acc[i][j] = z;

  for (int kt = 0; kt < K; kt += 64) {
#pragma unroll
    for (int it = 0; it < BM / 32; ++it) {
      int idx = it * 256 + tid;
      int r = idx >> 3, c = (idx & 7) * 8;
      g2lds16(A + (size_t)(m0 + r) * K + kt + c, (void*)(sA + idx * 8));
    }
#pragma unroll
    for (int it = 0; it < BN / 32; ++it) {
      int idx = it * 256 + tid;
      int r = idx >> 3, c = (idx & 7) * 8;
      g2lds16(Bt + (size_t)(n0 + r) * K + kt + c, (void*)(sB + idx * 8));
    }
    __syncthreads();
#pragma unroll
    for (int kk = 0; kk < 2; ++kk) {
      bf16x8 af[MF], bfr[NF];
#pragma unroll
      for (int f = 0; f < MF; ++f)
        af[f] = *(const bf16x8*)(sA + (wr * MF * 16 + f * 16 + l15) * 64 + kk * 32 + l4 * 8);
#pragma unroll
      for (int f = 0; f < NF; ++f)
        bfr[f] = *(const bf16x8*)(sB + (wc * NF * 16 + f * 16 + l15) * 64 + kk * 32 + l4 * 8);
#pragma unroll
      for (int mf = 0; mf < MF; ++mf)
#pragma unroll
        for (int nf = 0; nf < NF; ++nf)
          acc[mf][nf] =
              __builtin_amdgcn_mfma_f32_16x16x32_bf16(af[mf], bfr[nf], acc[mf][nf], 0, 0, 0);
    }
    __syncthreads();
  }

#pragma unroll
  for (int mf = 0; mf < MF; ++mf) {
#pragma unroll
    for (int nf = 0; nf < NF; ++nf) {
      int col = n0 + wc * NF * 16 + nf * 16 + l15;
      float bv = bias[col];
#pragma unroll
      for (int j = 0; j < 4; ++j) {
        int row = m0 + wr * MF * 16 + mf * 16 + l4 * 4 + j;
        size_t o = (size_t)row * N + col;
        float v = acc[mf][nf][j] + bv;
        if (EPI == 0) {
          ((__hip_bfloat16*)outp)[o] = __float2bfloat16(v);
        } else if (EPI == 1) {
          ((float*)outp)[o] = v + resid[o];
        } else {
          float a = 0.7978845608028654f * (v + 0.044715f * v * v * v);
          a = fminf(fmaxf(a, -15.f), 15.f);
          float e = __expf(2.f * a);
          float th = (e - 1.f) / (e + 1.f);
          ((__hip_bfloat16*)outp)[o] = __float2bfloat16(0.5f * v * (1.f + th));
        }
      }
    }
  }
}

// ===============================  Flash attention  =================================
// grid (S/128, B*H). 4 waves, each owns 32 q-rows (2 x 16-row fragments). KB=64.
// K/V double-buffered in LDS with XOR bank swizzle. One barrier per tile.
// Softmax: per-lane row-max tracking + __all() gate (defer-max THR=8 in log2 domain);
// full 16-lane reduce + acc rescale only when triggered.
__global__ __launch_bounds__(256) void attn_kernel(
    const __hip_bfloat16* __restrict__ qkv, const __hip_bfloat16* __restrict__ vT,
    __hip_bfloat16* __restrict__ out) {
  __shared__ alignas(16) __hip_bfloat16 sK[2][64 * 64];   // [kv][dh], swizzled
  __shared__ alignas(16) __hip_bfloat16 sV[2][64 * 64];   // [dh][kv], swizzled
  __shared__ alignas(16) __hip_bfloat16 sP[4][32 * 72];   // per-wave [q][kv] stride 72
  const int tid = threadIdx.x, lane = tid & 63, wave = tid >> 6;
  const int l15 = lane & 15, l4 = lane >> 4;
  const int bh = blockIdx.y, b = bh >> 4, h = bh & 15;
  const int q0 = blockIdx.x * 128;

  bf16x8 qf[2][2];
#pragma unroll
  for (int mf = 0; mf < 2; ++mf) {
    int qr = q0 + wave * 32 + mf * 16 + l15;
    const size_t qb = ((size_t)(b * S_ + qr)) * (3 * D_) + h * DH_;
    qf[mf][0] = *(const bf16x8*)(qkv + qb + l4 * 8);
    qf[mf][1] = *(const bf16x8*)(qkv + qb + 32 + l4 * 8);
  }

  f32x4 z = {0.f, 0.f, 0.f, 0.f};
  f32x4 acc[2][4];
#pragma unroll
  for (int mf = 0; mf < 2; ++mf)
#pragma unroll
    for (int nf = 0; nf < 4; ++nf) acc[mf][nf] = z;
  float mrun2[2][4], lrun[2][4];
#pragma unroll
  for (int mf = 0; mf < 2; ++mf)
#pragma unroll
    for (int j = 0; j < 4; ++j) { mrun2[mf][j] = -1e30f; lrun[mf][j] = 0.f; }

  const __hip_bfloat16* kg = qkv + (size_t)b * S_ * (3 * D_) + D_ + h * DH_;
  const __hip_bfloat16* vg = vT + (size_t)bh * DH_ * S_;

  auto stage = [&](int bu, int kv0) {
#pragma unroll
    for (int it = 0; it < 2; ++it) {
      int idx = it * 256 + tid;          // 0..511
      int r = idx >> 3;                  // 0..63
      int c = (idx & 7) * 8;             // 0..56
      int cs = c ^ ((r & 7) << 3);       // inverse-swizzled source column
      g2lds16(kg + (size_t)(kv0 + r) * (3 * D_) + cs, (void*)(&sK[bu][idx * 8]));
      g2lds16(vg + (size_t)r * S_ + kv0 + cs, (void*)(&sV[bu][idx * 8]));
    }
  };

  stage(0, 0);
  const float k2 = 0.125f * 1.44269504f;  // scale * log2(e)
  const int NT = S_ / 64;

  for (int t = 0; t < NT; ++t) {
    const int cur = t & 1;
    __syncthreads();                       // drains our stage loads; guards buf reuse
    if (t + 1 < NT) stage(cur ^ 1, (t + 1) * 64);

    // ---- QK^T ----
    f32x4 sf[2][4];
#pragma unroll
    for (int mf = 0; mf < 2; ++mf)
#pragma unroll
      for (int nf = 0; nf < 4; ++nf) sf[mf][nf] = z;
    __builtin_amdgcn_s_setprio(1);
#pragma unroll
    for (int ks = 0; ks < 2; ++ks) {
      int colsw = (ks * 32 + l4 * 8) ^ ((l15 & 7) << 3);
#pragma unroll
      for (int nf = 0; nf < 4; ++nf) {
        bf16x8 kf = *(const bf16x8*)(&sK[cur][(nf * 16 + l15) * 64 + colsw]);
        sf[0][nf] = __builtin_amdgcn_mfma_f32_16x16x32_bf16(qf[0][ks], kf, sf[0][nf], 0, 0, 0);
        sf[1][nf] = __builtin_amdgcn_mfma_f32_16x16x32_bf16(qf[1][ks], kf, sf[1][nf], 0, 0, 0);
      }
    }
    __builtin_amdgcn_s_setprio(0);

    // ---- online softmax: per-lane max + deferred reduce (THR=8 log2) ----
    float pm[2][4];
    float need = -1e30f;
#pragma unroll
    for (int mf = 0; mf < 2; ++mf)
#pragma unroll
      for (int j = 0; j < 4; ++j) {
        pm[mf][j] = fmaxf(fmaxf(sf[mf][0][j], sf[mf][1][j]),
                          fmaxf(sf[mf][2][j], sf[mf][3][j])) * k2;
        need = fmaxf(need, pm[mf][j] - mrun2[mf][j]);
      }
    if (!__all(need <= 8.0f)) {
#pragma unroll
      for (int mf = 0; mf < 2; ++mf)
#pragma unroll
        for (int j = 0; j < 4; ++j) {
          float m_ = pm[mf][j];
#pragma unroll
          for (int sh = 1; sh < 16; sh <<= 1) m_ = fmaxf(m_, __shfl_xor(m_, sh));
          float mn = fmaxf(mrun2[mf][j], m_);
          float corr = exp2f(mrun2[mf][j] - mn);
          mrun2[mf][j] = mn;
          lrun[mf][j] *= corr;
#pragma unroll
          for (int nf = 0; nf < 4; ++nf) acc[mf][nf][j] *= corr;
        }
    }
#pragma unroll
    for (int mf = 0; mf < 2; ++mf)
#pragma unroll
      for (int j = 0; j < 4; ++j) {
        float ps = 0.f;
#pragma unroll
        for (int nf = 0; nf < 4; ++nf) {
          float p = exp2f(sf[mf][nf][j] * k2 - mrun2[mf][j]);
          ps += p;
          sP[wave][(mf * 16 + l4 * 4 + j) * 72 + nf * 16 + l15] = __float2bfloat16(p);
        }
        lrun[mf][j] += ps;   // per-lane partial; reduced once in epilogue
      }

    // ---- PV ----
    __builtin_amdgcn_s_setprio(1);
#pragma unroll
    for (int ks = 0; ks < 2; ++ks) {
      int colsw = (ks * 32 + l4 * 8) ^ ((l15 & 7) << 3);
      bf16x8 pf0 = *(const bf16x8*)(&sP[wave][l15 * 72 + ks * 32 + l4 * 8]);
      bf16x8 pf1 = *(const bf16x8*)(&sP[wave][(16 + l15) * 72 + ks * 32 + l4 * 8]);
#pragma unroll
      for (int nf = 0; nf < 4; ++nf) {
        bf16x8 vf = *(const bf16x8*)(&sV[cur][(nf * 16 + l15) * 64 + colsw]);
        acc[0][nf] = __builtin_amdgcn_mfma_f32_16x16x32_bf16(pf0, vf, acc[0][nf], 0, 0, 0);
        acc[1][nf] = __builtin_amdgcn_mfma_f32_16x16x32_bf16(pf1, vf, acc[1][nf], 0, 0, 0);
      }
    }
    __builtin_amdgcn_s_setprio(0);
  }

  // ---- epilogue: finish row-sum reduce, normalize, store ----
#pragma unroll
  for (int mf = 0; mf < 2; ++mf)
#pragma unroll
    for (int j = 0; j < 4; ++j) {
      float l_ = lrun[mf][j];
#pragma unroll
      for (int sh = 1; sh < 16; sh <<= 1) l_ += __shfl_xor(l_, sh);
      float inv = 1.0f / l_;
      int row = q0 + wave * 32 + mf * 16 + l4 * 4 + j;
      size_t o = ((size_t)(b * S_ + row)) * D_ + h * DH_;
#pragma unroll
      for (int nf = 0; nf < 4; ++nf)
        out[o + nf * 16 + l15] = __float2bfloat16(acc[mf][nf][j] * inv);
    }
}

// ====================================================================================
extern "C" void kernel_launch(void* const* d_in, const int* in_sizes, int n_in,
                              void* d_out, int out_size, void* d_ws, size_t ws_size,
                              hipStream_t stream) {
  const float* x = (const float*)d_in[0];
  const float* ln1_g = (const float*)d_in[1];
  const float* ln1_b = (const float*)d_in[2];
  const float* Wqkv = (const float*)d_in[3];
  const float* bqkv = (const float*)d_in[4];
  const float* Wo = (const float*)d_in[5];
  const float* bo = (const float*)d_in[6];
  const float* ln2_g = (const float*)d_in[7];
  const float* ln2_b = (const float*)d_in[8];
  const float* W1 = (const float*)d_in[9];
  const float* b1 = (const float*)d_in[10];
  const float* W2 = (const float*)d_in[11];
  const float* b2 = (const float*)d_in[12];
  float* out = (float*)d_out;

  char* ws = (char*)d_ws;
  size_t off = 0;
  auto alloc = [&](size_t bytes) {
    void* p = ws + off;
    off += (bytes + 255) & ~(size_t)255;
    return p;
  };
  __hip_bfloat16* WqkvT = (__hip_bfloat16*)alloc((size_t)3 * D_ * D_ * 2);
  __hip_bfloat16* WoT = (__hip_bfloat16*)alloc((size_t)D_ * D_ * 2);
  __hip_bfloat16* W1T = (__hip_bfloat16*)alloc((size_t)FF_ * D_ * 2);
  __hip_bfloat16* W2T = (__hip_bfloat16*)alloc((size_t)D_ * FF_ * 2);
  __hip_bfloat16* h = (__hip_bfloat16*)alloc((size_t)MR_ * D_ * 2);
  __hip_bfloat16* qkv = (__hip_bfloat16*)alloc((size_t)MR_ * FF_ * 2);  // shared w/ ff
  __hip_bfloat16* ff = qkv;
  __hip_bfloat16* vT = (__hip_bfloat16*)alloc((size_t)B_ * H_ * DH_ * S_ * 2);
  __hip_bfloat16* attn_out = (__hip_bfloat16*)alloc((size_t)MR_ * D_ * 2);

  dim3 tb(32, 8);
  // 1. weight prep
  transpose_cvt<<<dim3(3 * D_ / 32, D_ / 32), tb, 0, stream>>>(Wqkv, WqkvT, D_, 3 * D_);
  transpose_cvt<<<dim3(D_ / 32, D_ / 32), tb, 0, stream>>>(Wo, WoT, D_, D_);
  transpose_cvt<<<dim3(FF_ / 32, D_ / 32), tb, 0, stream>>>(W1, W1T, D_, FF_);
  transpose_cvt<<<dim3(D_ / 32, FF_ / 32), tb, 0, stream>>>(W2, W2T, FF_, D_);
  // 2. LN1
  ln_kernel<<<MR_, 256, 0, stream>>>(x, ln1_g, ln1_b, h);
  // 3. QKV gemm (128x128 tile, 2x2 waves)
  gemm_bt<0, 128, 128, 2, 2><<<dim3(3 * D_ / 128, MR_ / 128), 256, 0, stream>>>(
      h, WqkvT, bqkv, nullptr, qkv, MR_, 3 * D_, D_);
  // 4. V transpose
  transpose_v<<<dim3(S_ / 32, DH_ / 32, B_ * H_), tb, 0, stream>>>(qkv, vT);
  // 5. attention
  attn_kernel<<<dim3(S_ / 128, B_ * H_), 256, 0, stream>>>(qkv, vT, attn_out);
  // 6. Wo gemm + residual -> d_out (x2, fp32). N=1024: 128x64 tile -> 512 blocks (2/CU)
  gemm_bt<1, 128, 64, 4, 1><<<dim3(D_ / 64, MR_ / 128), 256, 0, stream>>>(
      attn_out, WoT, bo, x, out, MR_, D_, D_);
  // 7. LN2 (reuse h)
  ln_kernel<<<MR_, 256, 0, stream>>>(out, ln2_g, ln2_b, h);
  // 8. W1 gemm + gelu (128x128 tile)
  gemm_bt<2, 128, 128, 2, 2><<<dim3(FF_ / 128, MR_ / 128), 256, 0, stream>>>(
      h, W1T, b1, nullptr, ff, MR_, FF_, D_);
  // 9. W2 gemm + residual(d_out) -> d_out. N=1024: 128x64 tile
  gemm_bt<1, 128, 64, 4, 1><<<dim3(D_ / 64, MR_ / 128), 256, 0, stream>>>(
      ff, W2T, b2, out, out, MR_, D_, FF_);
}

// Round 4
// 308.509 us; speedup vs baseline: 1.2854x; 1.0285x over previous
//
#include <hip/hip_runtime.h>
#include <hip/hip_bf16.h>
#include <cstdint>

#define D_ 1024
#define H_ 16
#define DH_ 64
#define FF_ 4096
#define B_ 2
#define S_ 2048
#define MR_ (B_ * S_)   // 4096 rows

typedef __bf16 bf16x8 __attribute__((ext_vector_type(8)));
typedef __bf16 bf16x4 __attribute__((ext_vector_type(4)));
typedef float f32x4 __attribute__((ext_vector_type(4)));

// ---- async global->LDS, 16B per lane (linear dest in lane order) ----
__device__ __forceinline__ void g2lds16(const void* g, void* l) {
  __builtin_amdgcn_global_load_lds(
      (__attribute__((address_space(1))) void*)(uintptr_t)g,
      (__attribute__((address_space(3))) void*)(uint32_t)(uintptr_t)l,
      16, 0, 0);
}

// =====================  weight transpose + fp32->bf16  =====================
// W [K,N] fp32 row-major  ->  Wt [N,K] bf16 row-major
__global__ __launch_bounds__(256) void transpose_cvt(
    const float* __restrict__ W, __hip_bfloat16* __restrict__ Wt, int K, int N) {
  __shared__ float t[32][33];
  int bx = blockIdx.x * 32;  // n
  int by = blockIdx.y * 32;  // k
  int tx = threadIdx.x, ty = threadIdx.y;  // (32,8)
#pragma unroll
  for (int i = 0; i < 4; ++i)
    t[ty + 8 * i][tx] = W[(size_t)(by + ty + 8 * i) * N + bx + tx];
  __syncthreads();
#pragma unroll
  for (int i = 0; i < 4; ++i)
    Wt[(size_t)(bx + ty + 8 * i) * K + by + tx] = __float2bfloat16(t[tx][ty + 8 * i]);
}

// ==============  V slice transpose: qkv[b,s, 2D + h*64 + d] -> vT[b,h,d,s]  ==========
__global__ __launch_bounds__(256) void transpose_v(
    const __hip_bfloat16* __restrict__ qkv, __hip_bfloat16* __restrict__ vT) {
  __shared__ __hip_bfloat16 t[32][33];
  int bh = blockIdx.z, b = bh >> 4, h = bh & 15;
  int s0 = blockIdx.x * 32, d0 = blockIdx.y * 32;
  int tx = threadIdx.x, ty = threadIdx.y;
#pragma unroll
  for (int i = 0; i < 4; ++i)
    t[ty + 8 * i][tx] =
        qkv[(size_t)(b * S_ + s0 + ty + 8 * i) * (3 * D_) + 2 * D_ + h * DH_ + d0 + tx];
  __syncthreads();
#pragma unroll
  for (int i = 0; i < 4; ++i)
    vT[(size_t)(bh * DH_ + d0 + ty + 8 * i) * S_ + s0 + tx] = t[tx][ty + 8 * i];
}

// ==========================  LayerNorm (fp32 in, bf16 out)  ========================
__global__ __launch_bounds__(256) void ln_kernel(
    const float* __restrict__ x, const float* __restrict__ g,
    const float* __restrict__ b, __hip_bfloat16* __restrict__ out) {
  int row = blockIdx.x;
  const float4* xr = (const float4*)(x + (size_t)row * D_);
  float4 v = xr[threadIdx.x];
  float s = v.x + v.y + v.z + v.w;
  float ss = v.x * v.x + v.y * v.y + v.z * v.z + v.w * v.w;
#pragma unroll
  for (int m = 1; m < 64; m <<= 1) {
    s += __shfl_xor(s, m);
    ss += __shfl_xor(ss, m);
  }
  __shared__ float rs[4], rss[4];
  int wave = threadIdx.x >> 6, lane = threadIdx.x & 63;
  if (lane == 0) { rs[wave] = s; rss[wave] = ss; }
  __syncthreads();
  s = rs[0] + rs[1] + rs[2] + rs[3];
  ss = rss[0] + rss[1] + rss[2] + rss[3];
  float mean = s * (1.0f / D_);
  float var = ss * (1.0f / D_) - mean * mean;
  float inv = rsqrtf(var + 1e-5f);
  int c = threadIdx.x * 4;
  float4 gv = ((const float4*)g)[threadIdx.x];
  float4 bv = ((const float4*)b)[threadIdx.x];
  __hip_bfloat16* o = out + (size_t)row * D_ + c;
  o[0] = __float2bfloat16((v.x - mean) * inv * gv.x + bv.x);
  o[1] = __float2bfloat16((v.y - mean) * inv * gv.y + bv.y);
  o[2] = __float2bfloat16((v.z - mean) * inv * gv.z + bv.z);
  o[3] = __float2bfloat16((v.w - mean) * inv * gv.w + bv.w);
}

// =====================  GEMM  C[M,N] = A[M,K] * Bt[N,K]^T + bias (+epilogue) ========
// EPI 0: bf16 out + bias;  1: f32 out + bias + resid;  2: bf16 out + bias + gelu
// Tile BM x BN, 4 waves arranged WM x WN (WM*WN==4). BK=64 fixed.
template <int EPI, int BM, int BN, int WM, int WN>
__global__ __launch_bounds__(256) void gemm_bt(
    const __hip_bfloat16* __restrict__ A, const __hip_bfloat16* __restrict__ Bt,
    const float* __restrict__ bias, const float* __restrict__ resid,
    void* __restrict__ outp, int M, int N, int K) {
  constexpr int MF = BM / (WM * 16);
  constexpr int NF = BN / (WN * 16);
  __shared__ alignas(16) __hip_bfloat16 sA[BM * 64];
  __shared__ alignas(16) __hip_bfloat16 sB[BN * 64];
  const int tid = threadIdx.x;
  const int lane = tid & 63, wave = tid >> 6;
  const int l15 = lane & 15, l4 = lane >> 4;
  const int wr = wave / WN, wc = wave % WN;
  const int m0 = blockIdx.y * BM, n0 = blockIdx.x * BN;

  f32x4 z = {0.f, 0.f, 0.f, 0.f};
  f32x4 acc[MF][NF];
#pragma unroll
  for (int i = 0; i < MF; ++i)
#pragma unroll
    for (int j = 0; j < NF; ++j) acc[i][j] = z;

  for (int kt = 0; kt < K; kt += 64) {
#pragma unroll
    for (int it = 0; it < BM / 32; ++it) {
      int idx = it * 256 + tid;
      int r = idx >> 3, c = (idx & 7) * 8;
      g2lds16(A + (size_t)(m0 + r) * K + kt + c, (void*)(sA + idx * 8));
    }
#pragma unroll
    for (int it = 0; it < BN / 32; ++it) {
      int idx = it * 256 + tid;
      int r = idx >> 3, c = (idx & 7) * 8;
      g2lds16(Bt + (size_t)(n0 + r) * K + kt + c, (void*)(sB + idx * 8));
    }
    __syncthreads();
#pragma unroll
    for (int kk = 0; kk < 2; ++kk) {
      bf16x8 af[MF], bfr[NF];
#pragma unroll
      for (int f = 0; f < MF; ++f)
        af[f] = *(const bf16x8*)(sA + (wr * MF * 16 + f * 16 + l15) * 64 + kk * 32 + l4 * 8);
#pragma unroll
      for (int f = 0; f < NF; ++f)
        bfr[f] = *(const bf16x8*)(sB + (wc * NF * 16 + f * 16 + l15) * 64 + kk * 32 + l4 * 8);
#pragma unroll
      for (int mf = 0; mf < MF; ++mf)
#pragma unroll
        for (int nf = 0; nf < NF; ++nf)
          acc[mf][nf] =
              __builtin_amdgcn_mfma_f32_16x16x32_bf16(af[mf], bfr[nf], acc[mf][nf], 0, 0, 0);
    }
    __syncthreads();
  }

#pragma unroll
  for (int mf = 0; mf < MF; ++mf) {
#pragma unroll
    for (int nf = 0; nf < NF; ++nf) {
      int col = n0 + wc * NF * 16 + nf * 16 + l15;
      float bv = bias[col];
#pragma unroll
      for (int j = 0; j < 4; ++j) {
        int row = m0 + wr * MF * 16 + mf * 16 + l4 * 4 + j;
        size_t o = (size_t)row * N + col;
        float v = acc[mf][nf][j] + bv;
        if (EPI == 0) {
          ((__hip_bfloat16*)outp)[o] = __float2bfloat16(v);
        } else if (EPI == 1) {
          ((float*)outp)[o] = v + resid[o];
        } else {
          float a = 0.7978845608028654f * (v + 0.044715f * v * v * v);
          a = fminf(fmaxf(a, -15.f), 15.f);
          float e = __expf(2.f * a);
          float th = (e - 1.f) / (e + 1.f);
          ((__hip_bfloat16*)outp)[o] = __float2bfloat16(0.5f * v * (1.f + th));
        }
      }
    }
  }
}

// ===============================  Flash attention (swapped-QK^T)  ==================
// grid (S/128, B*H). 4 waves, each owns 32 q-rows (2 x 16-col B-fragments). KB=64.
// QK^T computed as S^T = mfma(K_frag, Q_frag): lane holds one q-row (q=l15) of P
// -> packed b64 sP writes, contiguous b128 sP reads, lane-local softmax.
// PV computed as out^T = mfma(V^T_frag, P_frag). K/V double-buffered, XOR-swizzled.
__global__ __launch_bounds__(256) void attn_kernel(
    const __hip_bfloat16* __restrict__ qkv, const __hip_bfloat16* __restrict__ vT,
    __hip_bfloat16* __restrict__ out) {
  __shared__ alignas(16) __hip_bfloat16 sK[2][64 * 64];   // [kv][dh], swizzled
  __shared__ alignas(16) __hip_bfloat16 sV[2][64 * 64];   // [dh][kv], swizzled
  __shared__ alignas(16) __hip_bfloat16 sP[4][32 * 72];   // per-wave P[q][kv], stride 72
  const int tid = threadIdx.x, lane = tid & 63, wave = tid >> 6;
  const int l15 = lane & 15, l4 = lane >> 4;
  const int bh = blockIdx.y, b = bh >> 4, h = bh & 15;
  const int q0 = blockIdx.x * 128;

  // Q as B-operand: lane holds Q[q=l15][d = ks*32 + l4*8 + jj]
  bf16x8 qf[2][2];
#pragma unroll
  for (int qb = 0; qb < 2; ++qb) {
    int qr = q0 + wave * 32 + qb * 16 + l15;
    const size_t qbase = ((size_t)(b * S_ + qr)) * (3 * D_) + h * DH_;
    qf[qb][0] = *(const bf16x8*)(qkv + qbase + l4 * 8);
    qf[qb][1] = *(const bf16x8*)(qkv + qbase + 32 + l4 * 8);
  }

  f32x4 z = {0.f, 0.f, 0.f, 0.f};
  f32x4 acc[2][4];   // acc^T: [qb][dh-frag nf]; col=q=l15, row=dh=nf*16+l4*4+j
#pragma unroll
  for (int qb = 0; qb < 2; ++qb)
#pragma unroll
    for (int nf = 0; nf < 4; ++nf) acc[qb][nf] = z;
  float mrun[2] = {-1e30f, -1e30f};
  float lrun[2] = {0.f, 0.f};

  const __hip_bfloat16* kg = qkv + (size_t)b * S_ * (3 * D_) + D_ + h * DH_;
  const __hip_bfloat16* vg = vT + (size_t)bh * DH_ * S_;

  auto stage = [&](int bu, int kv0) {
#pragma unroll
    for (int it = 0; it < 2; ++it) {
      int idx = it * 256 + tid;          // 0..511
      int r = idx >> 3;                  // 0..63
      int c = (idx & 7) * 8;             // 0..56
      int cs = c ^ ((r & 7) << 3);       // inverse-swizzled source column
      g2lds16(kg + (size_t)(kv0 + r) * (3 * D_) + cs, (void*)(&sK[bu][idx * 8]));
      g2lds16(vg + (size_t)r * S_ + kv0 + cs, (void*)(&sV[bu][idx * 8]));
    }
  };

  stage(0, 0);
  const float k2 = 0.125f * 1.44269504f;  // scale * log2(e)
  const int NT = S_ / 64;

  for (int t = 0; t < NT; ++t) {
    const int cur = t & 1;
    __syncthreads();                       // drains our stage loads; guards buf reuse
    if (t + 1 < NT) stage(cur ^ 1, (t + 1) * 64);

    // ---- QK^T (swapped): sf[qb][kb] = S^T[kv = kb*16 + l4*4 + j][q = l15] ----
    f32x4 sf[2][4];
#pragma unroll
    for (int qb = 0; qb < 2; ++qb)
#pragma unroll
      for (int kb = 0; kb < 4; ++kb) sf[qb][kb] = z;
    __builtin_amdgcn_s_setprio(1);
#pragma unroll
    for (int ks = 0; ks < 2; ++ks) {
      int colsw = (ks * 32 + l4 * 8) ^ ((l15 & 7) << 3);
#pragma unroll
      for (int kb = 0; kb < 4; ++kb) {
        bf16x8 kf = *(const bf16x8*)(&sK[cur][(kb * 16 + l15) * 64 + colsw]);
        sf[0][kb] = __builtin_amdgcn_mfma_f32_16x16x32_bf16(kf, qf[0][ks], sf[0][kb], 0, 0, 0);
        sf[1][kb] = __builtin_amdgcn_mfma_f32_16x16x32_bf16(kf, qf[1][ks], sf[1][kb], 0, 0, 0);
      }
    }
    __builtin_amdgcn_s_setprio(0);

    // ---- softmax: each lane owns one q-row per qb (16 P values) ----
    float pm[2];
#pragma unroll
    for (int qb = 0; qb < 2; ++qb) {
      float a0 = fmaxf(fmaxf(sf[qb][0][0], sf[qb][0][1]), fmaxf(sf[qb][0][2], sf[qb][0][3]));
      float a1 = fmaxf(fmaxf(sf[qb][1][0], sf[qb][1][1]), fmaxf(sf[qb][1][2], sf[qb][1][3]));
      float a2 = fmaxf(fmaxf(sf[qb][2][0], sf[qb][2][1]), fmaxf(sf[qb][2][2], sf[qb][2][3]));
      float a3 = fmaxf(fmaxf(sf[qb][3][0], sf[qb][3][1]), fmaxf(sf[qb][3][2], sf[qb][3][3]));
      pm[qb] = fmaxf(fmaxf(a0, a1), fmaxf(a2, a3)) * k2;
    }
    float need = fmaxf(pm[0] - mrun[0], pm[1] - mrun[1]);
    if (!__all(need <= 8.0f)) {
#pragma unroll
      for (int qb = 0; qb < 2; ++qb) {
        float m_ = pm[qb];
        m_ = fmaxf(m_, __shfl_xor(m_, 16));
        m_ = fmaxf(m_, __shfl_xor(m_, 32));
        float mn = fmaxf(mrun[qb], m_);
        float corr = exp2f(mrun[qb] - mn);
        mrun[qb] = mn;
        lrun[qb] *= corr;
#pragma unroll
        for (int nf = 0; nf < 4; ++nf) acc[qb][nf] *= corr;
      }
    }
#pragma unroll
    for (int qb = 0; qb < 2; ++qb) {
      float ps = 0.f;
#pragma unroll
      for (int kb = 0; kb < 4; ++kb) {
        bf16x4 pv;
#pragma unroll
        for (int j = 0; j < 4; ++j) {
          float p = exp2f(sf[qb][kb][j] * k2 - mrun[qb]);
          ps += p;
          pv[j] = (__bf16)p;
        }
        *(bf16x4*)(&sP[wave][(qb * 16 + l15) * 72 + kb * 16 + l4 * 4]) = pv;
      }
      lrun[qb] += ps;   // per-lane partial over own kv; reduced in epilogue
    }

    // ---- PV (swapped): acc^T[qb][nf] += V^T_frag * P_frag ----
    __builtin_amdgcn_s_setprio(1);
#pragma unroll
    for (int ks = 0; ks < 2; ++ks) {
      int colsw = (ks * 32 + l4 * 8) ^ ((l15 & 7) << 3);
      bf16x8 pf0 = *(const bf16x8*)(&sP[wave][l15 * 72 + ks * 32 + l4 * 8]);
      bf16x8 pf1 = *(const bf16x8*)(&sP[wave][(16 + l15) * 72 + ks * 32 + l4 * 8]);
#pragma unroll
      for (int nf = 0; nf < 4; ++nf) {
        bf16x8 vf = *(const bf16x8*)(&sV[cur][(nf * 16 + l15) * 64 + colsw]);
        acc[0][nf] = __builtin_amdgcn_mfma_f32_16x16x32_bf16(vf, pf0, acc[0][nf], 0, 0, 0);
        acc[1][nf] = __builtin_amdgcn_mfma_f32_16x16x32_bf16(vf, pf1, acc[1][nf], 0, 0, 0);
      }
    }
    __builtin_amdgcn_s_setprio(0);
  }

  // ---- epilogue: reduce lrun across l4 groups, normalize, packed 8B stores ----
#pragma unroll
  for (int qb = 0; qb < 2; ++qb) {
    float l_ = lrun[qb];
    l_ += __shfl_xor(l_, 16);
    l_ += __shfl_xor(l_, 32);
    float inv = 1.0f / l_;
    int q = q0 + wave * 32 + qb * 16 + l15;
    size_t obase = ((size_t)(b * S_ + q)) * D_ + h * DH_;
#pragma unroll
    for (int nf = 0; nf < 4; ++nf) {
      bf16x4 ov;
#pragma unroll
      for (int j = 0; j < 4; ++j) ov[j] = (__bf16)(acc[qb][nf][j] * inv);
      *(bf16x4*)(out + obase + nf * 16 + l4 * 4) = ov;
    }
  }
}

// ====================================================================================
extern "C" void kernel_launch(void* const* d_in, const int* in_sizes, int n_in,
                              void* d_out, int out_size, void* d_ws, size_t ws_size,
                              hipStream_t stream) {
  const float* x = (const float*)d_in[0];
  const float* ln1_g = (const float*)d_in[1];
  const float* ln1_b = (const float*)d_in[2];
  const float* Wqkv = (const float*)d_in[3];
  const float* bqkv = (const float*)d_in[4];
  const float* Wo = (const float*)d_in[5];
  const float* bo = (const float*)d_in[6];
  const float* ln2_g = (const float*)d_in[7];
  const float* ln2_b = (const float*)d_in[8];
  const float* W1 = (const float*)d_in[9];
  const float* b1 = (const float*)d_in[10];
  const float* W2 = (const float*)d_in[11];
  const float* b2 = (const float*)d_in[12];
  float* out = (float*)d_out;

  char* ws = (char*)d_ws;
  size_t off = 0;
  auto alloc = [&](size_t bytes) {
    void* p = ws + off;
    off += (bytes + 255) & ~(size_t)255;
    return p;
  };
  __hip_bfloat16* WqkvT = (__hip_bfloat16*)alloc((size_t)3 * D_ * D_ * 2);
  __hip_bfloat16* WoT = (__hip_bfloat16*)alloc((size_t)D_ * D_ * 2);
  __hip_bfloat16* W1T = (__hip_bfloat16*)alloc((size_t)FF_ * D_ * 2);
  __hip_bfloat16* W2T = (__hip_bfloat16*)alloc((size_t)D_ * FF_ * 2);
  __hip_bfloat16* h = (__hip_bfloat16*)alloc((size_t)MR_ * D_ * 2);
  __hip_bfloat16* qkv = (__hip_bfloat16*)alloc((size_t)MR_ * FF_ * 2);  // shared w/ ff
  __hip_bfloat16* ff = qkv;
  __hip_bfloat16* vT = (__hip_bfloat16*)alloc((size_t)B_ * H_ * DH_ * S_ * 2);
  __hip_bfloat16* attn_out = (__hip_bfloat16*)alloc((size_t)MR_ * D_ * 2);

  dim3 tb(32, 8);
  // 1. weight prep
  transpose_cvt<<<dim3(3 * D_ / 32, D_ / 32), tb, 0, stream>>>(Wqkv, WqkvT, D_, 3 * D_);
  transpose_cvt<<<dim3(D_ / 32, D_ / 32), tb, 0, stream>>>(Wo, WoT, D_, D_);
  transpose_cvt<<<dim3(FF_ / 32, D_ / 32), tb, 0, stream>>>(W1, W1T, D_, FF_);
  transpose_cvt<<<dim3(D_ / 32, FF_ / 32), tb, 0, stream>>>(W2, W2T, FF_, D_);
  // 2. LN1
  ln_kernel<<<MR_, 256, 0, stream>>>(x, ln1_g, ln1_b, h);
  // 3. QKV gemm (128x128 tile, 2x2 waves)
  gemm_bt<0, 128, 128, 2, 2><<<dim3(3 * D_ / 128, MR_ / 128), 256, 0, stream>>>(
      h, WqkvT, bqkv, nullptr, qkv, MR_, 3 * D_, D_);
  // 4. V transpose
  transpose_v<<<dim3(S_ / 32, DH_ / 32, B_ * H_), tb, 0, stream>>>(qkv, vT);
  // 5. attention
  attn_kernel<<<dim3(S_ / 128, B_ * H_), 256, 0, stream>>>(qkv, vT, attn_out);
  // 6. Wo gemm + residual -> d_out (x2, fp32). N=1024: 128x64 tile -> 512 blocks (2/CU)
  gemm_bt<1, 128, 64, 4, 1><<<dim3(D_ / 64, MR_ / 128), 256, 0, stream>>>(
      attn_out, WoT, bo, x, out, MR_, D_, D_);
  // 7. LN2 (reuse h)
  ln_kernel<<<MR_, 256, 0, stream>>>(out, ln2_g, ln2_b, h);
  // 8. W1 gemm + gelu (128x128 tile)
  gemm_bt<2, 128, 128, 2, 2><<<dim3(FF_ / 128, MR_ / 128), 256, 0, stream>>>(
      h, W1T, b1, nullptr, ff, MR_, FF_, D_);
  // 9. W2 gemm + residual(d_out) -> d_out. N=1024: 128x64 tile
  gemm_bt<1, 128, 64, 4, 1><<<dim3(D_ / 64, MR_ / 128), 256, 0, stream>>>(
      ff, W2T, b2, out, out, MR_, D_, FF_);
}

// Round 5
// 304.616 us; speedup vs baseline: 1.3019x; 1.0128x over previous
//
#include <hip/hip_runtime.h>
#include <hip/hip_bf16.h>
#include <cstdint>

#define D_ 1024
#define H_ 16
#define DH_ 64
#define FF_ 4096
#define B_ 2
#define S_ 2048
#define MR_ (B_ * S_)   // 4096 rows

typedef __bf16 bf16x8 __attribute__((ext_vector_type(8)));
typedef __bf16 bf16x4 __attribute__((ext_vector_type(4)));
typedef float f32x4 __attribute__((ext_vector_type(4)));
typedef float f32x16 __attribute__((ext_vector_type(16)));

// ---- async global->LDS, 16B per lane (linear dest in lane order) ----
__device__ __forceinline__ void g2lds16(const void* g, void* l) {
  __builtin_amdgcn_global_load_lds(
      (__attribute__((address_space(1))) void*)(uintptr_t)g,
      (__attribute__((address_space(3))) void*)(uint32_t)(uintptr_t)l,
      16, 0, 0);
}

// pack two f32 -> one u32 holding 2 bf16 (lo, hi)
__device__ __forceinline__ unsigned pkbf16(float lo, float hi) {
  unsigned r;
  asm("v_cvt_pk_bf16_f32 %0, %1, %2" : "=v"(r) : "v"(lo), "v"(hi));
  return r;
}

// =====================  weight transpose + fp32->bf16  =====================
// W [K,N] fp32 row-major  ->  Wt [N,K] bf16 row-major
__global__ __launch_bounds__(256) void transpose_cvt(
    const float* __restrict__ W, __hip_bfloat16* __restrict__ Wt, int K, int N) {
  __shared__ float t[32][33];
  int bx = blockIdx.x * 32;  // n
  int by = blockIdx.y * 32;  // k
  int tx = threadIdx.x, ty = threadIdx.y;  // (32,8)
#pragma unroll
  for (int i = 0; i < 4; ++i)
    t[ty + 8 * i][tx] = W[(size_t)(by + ty + 8 * i) * N + bx + tx];
  __syncthreads();
#pragma unroll
  for (int i = 0; i < 4; ++i)
    Wt[(size_t)(bx + ty + 8 * i) * K + by + tx] = __float2bfloat16(t[tx][ty + 8 * i]);
}

// ==============  V slice transpose: qkv[b,s, 2D + h*64 + d] -> vT[b,h,d,s]  ==========
__global__ __launch_bounds__(256) void transpose_v(
    const __hip_bfloat16* __restrict__ qkv, __hip_bfloat16* __restrict__ vT) {
  __shared__ __hip_bfloat16 t[32][33];
  int bh = blockIdx.z, b = bh >> 4, h = bh & 15;
  int s0 = blockIdx.x * 32, d0 = blockIdx.y * 32;
  int tx = threadIdx.x, ty = threadIdx.y;
#pragma unroll
  for (int i = 0; i < 4; ++i)
    t[ty + 8 * i][tx] =
        qkv[(size_t)(b * S_ + s0 + ty + 8 * i) * (3 * D_) + 2 * D_ + h * DH_ + d0 + tx];
  __syncthreads();
#pragma unroll
  for (int i = 0; i < 4; ++i)
    vT[(size_t)(bh * DH_ + d0 + ty + 8 * i) * S_ + s0 + tx] = t[tx][ty + 8 * i];
}

// ==========================  LayerNorm (fp32 in, bf16 out)  ========================
__global__ __launch_bounds__(256) void ln_kernel(
    const float* __restrict__ x, const float* __restrict__ g,
    const float* __restrict__ b, __hip_bfloat16* __restrict__ out) {
  int row = blockIdx.x;
  const float4* xr = (const float4*)(x + (size_t)row * D_);
  float4 v = xr[threadIdx.x];
  float s = v.x + v.y + v.z + v.w;
  float ss = v.x * v.x + v.y * v.y + v.z * v.z + v.w * v.w;
#pragma unroll
  for (int m = 1; m < 64; m <<= 1) {
    s += __shfl_xor(s, m);
    ss += __shfl_xor(ss, m);
  }
  __shared__ float rs[4], rss[4];
  int wave = threadIdx.x >> 6, lane = threadIdx.x & 63;
  if (lane == 0) { rs[wave] = s; rss[wave] = ss; }
  __syncthreads();
  s = rs[0] + rs[1] + rs[2] + rs[3];
  ss = rss[0] + rss[1] + rss[2] + rss[3];
  float mean = s * (1.0f / D_);
  float var = ss * (1.0f / D_) - mean * mean;
  float inv = rsqrtf(var + 1e-5f);
  int c = threadIdx.x * 4;
  float4 gv = ((const float4*)g)[threadIdx.x];
  float4 bv = ((const float4*)b)[threadIdx.x];
  __hip_bfloat16* o = out + (size_t)row * D_ + c;
  o[0] = __float2bfloat16((v.x - mean) * inv * gv.x + bv.x);
  o[1] = __float2bfloat16((v.y - mean) * inv * gv.y + bv.y);
  o[2] = __float2bfloat16((v.z - mean) * inv * gv.z + bv.z);
  o[3] = __float2bfloat16((v.w - mean) * inv * gv.w + bv.w);
}

// =====================  GEMM  C[M,N] = A[M,K] * Bt[N,K]^T + bias (+epilogue) ========
// EPI 0: bf16 out + bias;  1: f32 out + bias + resid;  2: bf16 out + bias + gelu
// Tile BM x BN, 4 waves arranged WM x WN (WM*WN==4). BK=64 fixed.
template <int EPI, int BM, int BN, int WM, int WN>
__global__ __launch_bounds__(256) void gemm_bt(
    const __hip_bfloat16* __restrict__ A, const __hip_bfloat16* __restrict__ Bt,
    const float* __restrict__ bias, const float* __restrict__ resid,
    void* __restrict__ outp, int M, int N, int K) {
  constexpr int MF = BM / (WM * 16);
  constexpr int NF = BN / (WN * 16);
  __shared__ alignas(16) __hip_bfloat16 sA[BM * 64];
  __shared__ alignas(16) __hip_bfloat16 sB[BN * 64];
  const int tid = threadIdx.x;
  const int lane = tid & 63, wave = tid >> 6;
  const int l15 = lane & 15, l4 = lane >> 4;
  const int wr = wave / WN, wc = wave % WN;
  const int m0 = blockIdx.y * BM, n0 = blockIdx.x * BN;

  f32x4 z = {0.f, 0.f, 0.f, 0.f};
  f32x4 acc[MF][NF];
#pragma unroll
  for (int i = 0; i < MF; ++i)
#pragma unroll
    for (int j = 0; j < NF; ++j) acc[i][j] = z;

  for (int kt = 0; kt < K; kt += 64) {
#pragma unroll
    for (int it = 0; it < BM / 32; ++it) {
      int idx = it * 256 + tid;
      int r = idx >> 3, c = (idx & 7) * 8;
      g2lds16(A + (size_t)(m0 + r) * K + kt + c, (void*)(sA + idx * 8));
    }
#pragma unroll
    for (int it = 0; it < BN / 32; ++it) {
      int idx = it * 256 + tid;
      int r = idx >> 3, c = (idx & 7) * 8;
      g2lds16(Bt + (size_t)(n0 + r) * K + kt + c, (void*)(sB + idx * 8));
    }
    __syncthreads();
#pragma unroll
    for (int kk = 0; kk < 2; ++kk) {
      bf16x8 af[MF], bfr[NF];
#pragma unroll
      for (int f = 0; f < MF; ++f)
        af[f] = *(const bf16x8*)(sA + (wr * MF * 16 + f * 16 + l15) * 64 + kk * 32 + l4 * 8);
#pragma unroll
      for (int f = 0; f < NF; ++f)
        bfr[f] = *(const bf16x8*)(sB + (wc * NF * 16 + f * 16 + l15) * 64 + kk * 32 + l4 * 8);
#pragma unroll
      for (int mf = 0; mf < MF; ++mf)
#pragma unroll
        for (int nf = 0; nf < NF; ++nf)
          acc[mf][nf] =
              __builtin_amdgcn_mfma_f32_16x16x32_bf16(af[mf], bfr[nf], acc[mf][nf], 0, 0, 0);
    }
    __syncthreads();
  }

#pragma unroll
  for (int mf = 0; mf < MF; ++mf) {
#pragma unroll
    for (int nf = 0; nf < NF; ++nf) {
      int col = n0 + wc * NF * 16 + nf * 16 + l15;
      float bv = bias[col];
#pragma unroll
      for (int j = 0; j < 4; ++j) {
        int row = m0 + wr * MF * 16 + mf * 16 + l4 * 4 + j;
        size_t o = (size_t)row * N + col;
        float v = acc[mf][nf][j] + bv;
        if (EPI == 0) {
          ((__hip_bfloat16*)outp)[o] = __float2bfloat16(v);
        } else if (EPI == 1) {
          ((float*)outp)[o] = v + resid[o];
        } else {
          float a = 0.7978845608028654f * (v + 0.044715f * v * v * v);
          a = fminf(fmaxf(a, -15.f), 15.f);
          float e = __expf(2.f * a);
          float th = (e - 1.f) / (e + 1.f);
          ((__hip_bfloat16*)outp)[o] = __float2bfloat16(0.5f * v * (1.f + th));
        }
      }
    }
  }
}

// ===============  Flash attention: 32x32 MFMA, in-register softmax  ================
// grid (S/128, B*H). 4 waves x 32 q-rows. KB=64, K/V double-buffered + XOR swizzle.
// Swapped QK^T: S^T = mfma_32x32x16(K_frag, Q_frag) -> lane owns one q-col (q=lane&31),
// 32 kv-scores split across lane+-32. Softmax lane-local; P packed via v_cvt_pk_bf16
// + permlane32_swap directly into PV A-fragments (no LDS P round-trip).
// PV: D[q][dh] = mfma_32x32x16(P_frag, V^T_frag). Per-q state broadcast to acc rows
// via tiny per-wave LDS array (trigger-only + epilogue).
__global__ __launch_bounds__(256) void attn_kernel(
    const __hip_bfloat16* __restrict__ qkv, const __hip_bfloat16* __restrict__ vT,
    __hip_bfloat16* __restrict__ out) {
  __shared__ alignas(16) __hip_bfloat16 sK[2][64 * 64];   // [kv][dh], swizzled
  __shared__ alignas(16) __hip_bfloat16 sV[2][64 * 64];   // [dh][kv], swizzled
  __shared__ float sBr[4][32];                            // per-wave q-broadcast
  const int tid = threadIdx.x, lane = tid & 63, wave = tid >> 6;
  const int l31 = lane & 31, hi = lane >> 5;
  const int bh = blockIdx.y, b = bh >> 4, h = bh & 15;
  const int q0 = blockIdx.x * 128;
  const int rsw = (l31 & 7) << 3;

  // Q as B-operand: lane holds Q[q = l31][d = ks*16 + hi*8 + jj]
  bf16x8 qf[4];
  {
    int qr = q0 + wave * 32 + l31;
    const size_t qbase = ((size_t)(b * S_ + qr)) * (3 * D_) + h * DH_;
#pragma unroll
    for (int ks = 0; ks < 4; ++ks)
      qf[ks] = *(const bf16x8*)(qkv + qbase + ks * 16 + hi * 8);
  }

  f32x16 acc0, acc1;   // D[q][dh]: col = dh = l31 (+32 for acc1), rows = q(reg)
#pragma unroll
  for (int r = 0; r < 16; ++r) { acc0[r] = 0.f; acc1[r] = 0.f; }
  float mrun = -1e30f, lrun = 0.f;   // per-lane, for q = l31

  const __hip_bfloat16* kg = qkv + (size_t)b * S_ * (3 * D_) + D_ + h * DH_;
  const __hip_bfloat16* vg = vT + (size_t)bh * DH_ * S_;

  auto stage = [&](int bu, int kv0) {
#pragma unroll
    for (int it = 0; it < 2; ++it) {
      int idx = it * 256 + tid;          // 0..511
      int r = idx >> 3;                  // 0..63
      int c = (idx & 7) * 8;             // 0..56
      int cs = c ^ ((r & 7) << 3);       // inverse-swizzled source column
      g2lds16(kg + (size_t)(kv0 + r) * (3 * D_) + cs, (void*)(&sK[bu][idx * 8]));
      g2lds16(vg + (size_t)r * S_ + kv0 + cs, (void*)(&sV[bu][idx * 8]));
    }
  };

  stage(0, 0);
  const float k2 = 0.125f * 1.44269504f;  // scale * log2(e)
  const int NT = S_ / 64;

  for (int t = 0; t < NT; ++t) {
    const int cur = t & 1;
    __syncthreads();                       // drains our stage loads; guards buf reuse
    if (t + 1 < NT) stage(cur ^ 1, (t + 1) * 64);

    // ---- QK^T (swapped, 32x32x16): sf{0,1} = S^T[kv-block][q=l31] ----
    f32x16 sf0, sf1;
#pragma unroll
    for (int r = 0; r < 16; ++r) { sf0[r] = 0.f; sf1[r] = 0.f; }
    __builtin_amdgcn_s_setprio(1);
#pragma unroll
    for (int ks = 0; ks < 4; ++ks) {
      int colsw = (ks * 16 + hi * 8) ^ rsw;
      bf16x8 kf0 = *(const bf16x8*)(&sK[cur][l31 * 64 + colsw]);
      bf16x8 kf1 = *(const bf16x8*)(&sK[cur][(32 + l31) * 64 + colsw]);
      sf0 = __builtin_amdgcn_mfma_f32_32x32x16_bf16(kf0, qf[ks], sf0, 0, 0, 0);
      sf1 = __builtin_amdgcn_mfma_f32_32x32x16_bf16(kf1, qf[ks], sf1, 0, 0, 0);
    }
    __builtin_amdgcn_s_setprio(0);

    // ---- lane-local max + defer-max gate (THR=8 in log2 domain) ----
    float m0 = fmaxf(fmaxf(fmaxf(sf0[0], sf0[1]), fmaxf(sf0[2], sf0[3])),
                     fmaxf(fmaxf(sf0[4], sf0[5]), fmaxf(sf0[6], sf0[7])));
    float m1 = fmaxf(fmaxf(fmaxf(sf0[8], sf0[9]), fmaxf(sf0[10], sf0[11])),
                     fmaxf(fmaxf(sf0[12], sf0[13]), fmaxf(sf0[14], sf0[15])));
    float m2 = fmaxf(fmaxf(fmaxf(sf1[0], sf1[1]), fmaxf(sf1[2], sf1[3])),
                     fmaxf(fmaxf(sf1[4], sf1[5]), fmaxf(sf1[6], sf1[7])));
    float m3 = fmaxf(fmaxf(fmaxf(sf1[8], sf1[9]), fmaxf(sf1[10], sf1[11])),
                     fmaxf(fmaxf(sf1[12], sf1[13]), fmaxf(sf1[14], sf1[15])));
    float pm = fmaxf(fmaxf(m0, m1), fmaxf(m2, m3)) * k2;
    if (!__all(pm - mrun <= 8.0f)) {
      float mf = fmaxf(pm, __shfl_xor(pm, 32));
      float mn = fmaxf(mrun, mf);
      float corrl = exp2f(mrun - mn);
      mrun = mn;
      lrun *= corrl;
      sBr[wave][l31] = corrl;            // lanes l31 & l31+32 write same value
#pragma unroll
      for (int r = 0; r < 16; ++r) {
        float cr = sBr[wave][(r & 3) + 8 * (r >> 2) + 4 * hi];
        acc0[r] *= cr;
        acc1[r] *= cr;
      }
    }

    // ---- P = exp2(S*k2 - m), pack to bf16, permlane into PV A-fragments ----
    bf16x8 pa[4];
    float ps = 0.f;
#pragma unroll
    for (int kb = 0; kb < 2; ++kb) {
      const f32x16 s16 = kb ? sf1 : sf0;
#pragma unroll
      for (int ksb = 0; ksb < 2; ++ksb) {
        float p0 = exp2f(s16[8 * ksb + 0] * k2 - mrun);
        float p1 = exp2f(s16[8 * ksb + 1] * k2 - mrun);
        float p2 = exp2f(s16[8 * ksb + 2] * k2 - mrun);
        float p3 = exp2f(s16[8 * ksb + 3] * k2 - mrun);
        float p4 = exp2f(s16[8 * ksb + 4] * k2 - mrun);
        float p5 = exp2f(s16[8 * ksb + 5] * k2 - mrun);
        float p6 = exp2f(s16[8 * ksb + 6] * k2 - mrun);
        float p7 = exp2f(s16[8 * ksb + 7] * k2 - mrun);
        ps += ((p0 + p1) + (p2 + p3)) + ((p4 + p5) + (p6 + p7));
        unsigned wa = pkbf16(p0, p1), wb = pkbf16(p2, p3);
        unsigned wc = pkbf16(p4, p5), wd = pkbf16(p6, p7);
        auto r1 = __builtin_amdgcn_permlane32_swap(wa, wc, false, false);
        auto r2 = __builtin_amdgcn_permlane32_swap(wb, wd, false, false);
        union { unsigned u[4]; bf16x8 v; } w;
        w.u[0] = r1[0]; w.u[1] = r2[0]; w.u[2] = r1[1]; w.u[3] = r2[1];
        pa[kb * 2 + ksb] = w.v;
      }
    }
    lrun += ps;

    // ---- PV: acc[q][dh] += P_frag x V^T_frag ----
    __builtin_amdgcn_s_setprio(1);
#pragma unroll
    for (int ksg = 0; ksg < 4; ++ksg) {
      int colsw = (ksg * 16 + hi * 8) ^ rsw;
      bf16x8 vf0 = *(const bf16x8*)(&sV[cur][l31 * 64 + colsw]);
      bf16x8 vf1 = *(const bf16x8*)(&sV[cur][(32 + l31) * 64 + colsw]);
      acc0 = __builtin_amdgcn_mfma_f32_32x32x16_bf16(pa[ksg], vf0, acc0, 0, 0, 0);
      acc1 = __builtin_amdgcn_mfma_f32_32x32x16_bf16(pa[ksg], vf1, acc1, 0, 0, 0);
    }
    __builtin_amdgcn_s_setprio(0);
  }

  // ---- epilogue: row-sum across lane pair, broadcast inv per q-row, store ----
  float lt = lrun + __shfl_xor(lrun, 32);
  float inv = 1.0f / lt;
  sBr[wave][l31] = inv;                  // both half-lanes write same value
#pragma unroll
  for (int r = 0; r < 16; ++r) {
    int qrow = (r & 3) + 8 * (r >> 2) + 4 * hi;
    float ir = sBr[wave][qrow];
    size_t obase = ((size_t)(b * S_ + q0 + wave * 32 + qrow)) * D_ + h * DH_ + l31;
    out[obase] = __float2bfloat16(acc0[r] * ir);
    out[obase + 32] = __float2bfloat16(acc1[r] * ir);
  }
}

// ====================================================================================
extern "C" void kernel_launch(void* const* d_in, const int* in_sizes, int n_in,
                              void* d_out, int out_size, void* d_ws, size_t ws_size,
                              hipStream_t stream) {
  const float* x = (const float*)d_in[0];
  const float* ln1_g = (const float*)d_in[1];
  const float* ln1_b = (const float*)d_in[2];
  const float* Wqkv = (const float*)d_in[3];
  const float* bqkv = (const float*)d_in[4];
  const float* Wo = (const float*)d_in[5];
  const float* bo = (const float*)d_in[6];
  const float* ln2_g = (const float*)d_in[7];
  const float* ln2_b = (const float*)d_in[8];
  const float* W1 = (const float*)d_in[9];
  const float* b1 = (const float*)d_in[10];
  const float* W2 = (const float*)d_in[11];
  const float* b2 = (const float*)d_in[12];
  float* out = (float*)d_out;

  char* ws = (char*)d_ws;
  size_t off = 0;
  auto alloc = [&](size_t bytes) {
    void* p = ws + off;
    off += (bytes + 255) & ~(size_t)255;
    return p;
  };
  __hip_bfloat16* WqkvT = (__hip_bfloat16*)alloc((size_t)3 * D_ * D_ * 2);
  __hip_bfloat16* WoT = (__hip_bfloat16*)alloc((size_t)D_ * D_ * 2);
  __hip_bfloat16* W1T = (__hip_bfloat16*)alloc((size_t)FF_ * D_ * 2);
  __hip_bfloat16* W2T = (__hip_bfloat16*)alloc((size_t)D_ * FF_ * 2);
  __hip_bfloat16* h = (__hip_bfloat16*)alloc((size_t)MR_ * D_ * 2);
  __hip_bfloat16* qkv = (__hip_bfloat16*)alloc((size_t)MR_ * FF_ * 2);  // shared w/ ff
  __hip_bfloat16* ff = qkv;
  __hip_bfloat16* vT = (__hip_bfloat16*)alloc((size_t)B_ * H_ * DH_ * S_ * 2);
  __hip_bfloat16* attn_out = (__hip_bfloat16*)alloc((size_t)MR_ * D_ * 2);

  dim3 tb(32, 8);
  // 1. weight prep
  transpose_cvt<<<dim3(3 * D_ / 32, D_ / 32), tb, 0, stream>>>(Wqkv, WqkvT, D_, 3 * D_);
  transpose_cvt<<<dim3(D_ / 32, D_ / 32), tb, 0, stream>>>(Wo, WoT, D_, D_);
  transpose_cvt<<<dim3(FF_ / 32, D_ / 32), tb, 0, stream>>>(W1, W1T, D_, FF_);
  transpose_cvt<<<dim3(D_ / 32, FF_ / 32), tb, 0, stream>>>(W2, W2T, FF_, D_);
  // 2. LN1
  ln_kernel<<<MR_, 256, 0, stream>>>(x, ln1_g, ln1_b, h);
  // 3. QKV gemm (128x128 tile, 2x2 waves)
  gemm_bt<0, 128, 128, 2, 2><<<dim3(3 * D_ / 128, MR_ / 128), 256, 0, stream>>>(
      h, WqkvT, bqkv, nullptr, qkv, MR_, 3 * D_, D_);
  // 4. V transpose
  transpose_v<<<dim3(S_ / 32, DH_ / 32, B_ * H_), tb, 0, stream>>>(qkv, vT);
  // 5. attention
  attn_kernel<<<dim3(S_ / 128, B_ * H_), 256, 0, stream>>>(qkv, vT, attn_out);
  // 6. Wo gemm + residual -> d_out (x2, fp32). N=1024: 128x64 tile -> 512 blocks (2/CU)
  gemm_bt<1, 128, 64, 4, 1><<<dim3(D_ / 64, MR_ / 128), 256, 0, stream>>>(
      attn_out, WoT, bo, x, out, MR_, D_, D_);
  // 7. LN2 (reuse h)
  ln_kernel<<<MR_, 256, 0, stream>>>(out, ln2_g, ln2_b, h);
  // 8. W1 gemm + gelu (128x128 tile)
  gemm_bt<2, 128, 128, 2, 2><<<dim3(FF_ / 128, MR_ / 128), 256, 0, stream>>>(
      h, W1T, b1, nullptr, ff, MR_, FF_, D_);
  // 9. W2 gemm + residual(d_out) -> d_out. N=1024: 128x64 tile
  gemm_bt<1, 128, 64, 4, 1><<<dim3(D_ / 64, MR_ / 128), 256, 0, stream>>>(
      ff, W2T, b2, out, out, MR_, D_, FF_);
}

// Round 6
// 281.168 us; speedup vs baseline: 1.4104x; 1.0834x over previous
//
#include <hip/hip_runtime.h>
#include <hip/hip_bf16.h>
#include <cstdint>

#define D_ 1024
#define H_ 16
#define DH_ 64
#define FF_ 4096
#define B_ 2
#define S_ 2048
#define MR_ (B_ * S_)   // 4096 rows

typedef __bf16 bf16x8 __attribute__((ext_vector_type(8)));
typedef __bf16 bf16x4 __attribute__((ext_vector_type(4)));
typedef float f32x4 __attribute__((ext_vector_type(4)));
typedef float f32x16 __attribute__((ext_vector_type(16)));

// ---- async global->LDS, 16B per lane (linear dest in lane order) ----
__device__ __forceinline__ void g2lds16(const void* g, void* l) {
  __builtin_amdgcn_global_load_lds(
      (__attribute__((address_space(1))) void*)(uintptr_t)g,
      (__attribute__((address_space(3))) void*)(uint32_t)(uintptr_t)l,
      16, 0, 0);
}

// pack two f32 -> one u32 holding 2 bf16 (lo, hi)
__device__ __forceinline__ unsigned pkbf16(float lo, float hi) {
  unsigned r;
  asm("v_cvt_pk_bf16_f32 %0, %1, %2" : "=v"(r) : "v"(lo), "v"(hi));
  return r;
}

__device__ __forceinline__ float max3f(float a, float b, float c) {
  float d;
  asm("v_max3_f32 %0, %1, %2, %3" : "=v"(d) : "v"(a), "v"(b), "v"(c));
  return d;
}

__device__ __forceinline__ float rmax16(const f32x16& v) {
  float t0 = max3f(v[0], v[1], v[2]);
  float t1 = max3f(v[3], v[4], v[5]);
  float t2 = max3f(v[6], v[7], v[8]);
  float t3 = max3f(v[9], v[10], v[11]);
  float t4 = max3f(v[12], v[13], v[14]);
  return fmaxf(max3f(t0, t1, t2), max3f(t3, t4, v[15]));
}

// =====================  weight transpose + fp32->bf16  =====================
// W [K,N] fp32 row-major  ->  Wt [N,K] bf16 row-major
__global__ __launch_bounds__(256) void transpose_cvt(
    const float* __restrict__ W, __hip_bfloat16* __restrict__ Wt, int K, int N) {
  __shared__ float t[32][33];
  int bx = blockIdx.x * 32;  // n
  int by = blockIdx.y * 32;  // k
  int tx = threadIdx.x, ty = threadIdx.y;  // (32,8)
#pragma unroll
  for (int i = 0; i < 4; ++i)
    t[ty + 8 * i][tx] = W[(size_t)(by + ty + 8 * i) * N + bx + tx];
  __syncthreads();
#pragma unroll
  for (int i = 0; i < 4; ++i)
    Wt[(size_t)(bx + ty + 8 * i) * K + by + tx] = __float2bfloat16(t[tx][ty + 8 * i]);
}

// ==============  V slice transpose: qkv[b,s, 2D + h*64 + d] -> vT[b,h,d,s]  ==========
__global__ __launch_bounds__(256) void transpose_v(
    const __hip_bfloat16* __restrict__ qkv, __hip_bfloat16* __restrict__ vT) {
  __shared__ __hip_bfloat16 t[32][33];
  int bh = blockIdx.z, b = bh >> 4, h = bh & 15;
  int s0 = blockIdx.x * 32, d0 = blockIdx.y * 32;
  int tx = threadIdx.x, ty = threadIdx.y;
#pragma unroll
  for (int i = 0; i < 4; ++i)
    t[ty + 8 * i][tx] =
        qkv[(size_t)(b * S_ + s0 + ty + 8 * i) * (3 * D_) + 2 * D_ + h * DH_ + d0 + tx];
  __syncthreads();
#pragma unroll
  for (int i = 0; i < 4; ++i)
    vT[(size_t)(bh * DH_ + d0 + ty + 8 * i) * S_ + s0 + tx] = t[tx][ty + 8 * i];
}

// ==========================  LayerNorm (fp32 in, bf16 out)  ========================
__global__ __launch_bounds__(256) void ln_kernel(
    const float* __restrict__ x, const float* __restrict__ g,
    const float* __restrict__ b, __hip_bfloat16* __restrict__ out) {
  int row = blockIdx.x;
  const float4* xr = (const float4*)(x + (size_t)row * D_);
  float4 v = xr[threadIdx.x];
  float s = v.x + v.y + v.z + v.w;
  float ss = v.x * v.x + v.y * v.y + v.z * v.z + v.w * v.w;
#pragma unroll
  for (int m = 1; m < 64; m <<= 1) {
    s += __shfl_xor(s, m);
    ss += __shfl_xor(ss, m);
  }
  __shared__ float rs[4], rss[4];
  int wave = threadIdx.x >> 6, lane = threadIdx.x & 63;
  if (lane == 0) { rs[wave] = s; rss[wave] = ss; }
  __syncthreads();
  s = rs[0] + rs[1] + rs[2] + rs[3];
  ss = rss[0] + rss[1] + rss[2] + rss[3];
  float mean = s * (1.0f / D_);
  float var = ss * (1.0f / D_) - mean * mean;
  float inv = rsqrtf(var + 1e-5f);
  int c = threadIdx.x * 4;
  float4 gv = ((const float4*)g)[threadIdx.x];
  float4 bv = ((const float4*)b)[threadIdx.x];
  __hip_bfloat16* o = out + (size_t)row * D_ + c;
  o[0] = __float2bfloat16((v.x - mean) * inv * gv.x + bv.x);
  o[1] = __float2bfloat16((v.y - mean) * inv * gv.y + bv.y);
  o[2] = __float2bfloat16((v.z - mean) * inv * gv.z + bv.z);
  o[3] = __float2bfloat16((v.w - mean) * inv * gv.w + bv.w);
}

// =====================  GEMM  C[M,N] = A[M,K] * Bt[N,K]^T + bias (+epilogue) ========
// EPI 0: bf16 out + bias;  1: f32 out + bias + resid;  2: bf16 out + bias + gelu
// Tile BM x BN, 4 waves arranged WM x WN (WM*WN==4). BK=64 fixed.
// DBUF: double-buffered LDS, stage(t+1) issued before compute(t), 1 barrier/iter.
template <int EPI, int BM, int BN, int WM, int WN, bool DBUF>
__global__ __launch_bounds__(256) void gemm_bt(
    const __hip_bfloat16* __restrict__ A, const __hip_bfloat16* __restrict__ Bt,
    const float* __restrict__ bias, const float* __restrict__ resid,
    void* __restrict__ outp, int M, int N, int K) {
  constexpr int MF = BM / (WM * 16);
  constexpr int NF = BN / (WN * 16);
  constexpr int NB = DBUF ? 2 : 1;
  __shared__ alignas(16) __hip_bfloat16 sA[NB][BM * 64];
  __shared__ alignas(16) __hip_bfloat16 sB[NB][BN * 64];
  const int tid = threadIdx.x;
  const int lane = tid & 63, wave = tid >> 6;
  const int l15 = lane & 15, l4 = lane >> 4;
  const int wr = wave / WN, wc = wave % WN;
  const int m0 = blockIdx.y * BM, n0 = blockIdx.x * BN;

  f32x4 z = {0.f, 0.f, 0.f, 0.f};
  f32x4 acc[MF][NF];
#pragma unroll
  for (int i = 0; i < MF; ++i)
#pragma unroll
    for (int j = 0; j < NF; ++j) acc[i][j] = z;

  auto stage = [&](int bu, int kt) {
#pragma unroll
    for (int it = 0; it < BM / 32; ++it) {
      int idx = it * 256 + tid;
      int r = idx >> 3, c = (idx & 7) * 8;
      g2lds16(A + (size_t)(m0 + r) * K + kt + c, (void*)(&sA[bu][idx * 8]));
    }
#pragma unroll
    for (int it = 0; it < BN / 32; ++it) {
      int idx = it * 256 + tid;
      int r = idx >> 3, c = (idx & 7) * 8;
      g2lds16(Bt + (size_t)(n0 + r) * K + kt + c, (void*)(&sB[bu][idx * 8]));
    }
  };

  auto compute = [&](int bu) {
#pragma unroll
    for (int kk = 0; kk < 2; ++kk) {
      bf16x8 af[MF], bfr[NF];
#pragma unroll
      for (int f = 0; f < MF; ++f)
        af[f] = *(const bf16x8*)(&sA[bu][(wr * MF * 16 + f * 16 + l15) * 64 + kk * 32 + l4 * 8]);
#pragma unroll
      for (int f = 0; f < NF; ++f)
        bfr[f] = *(const bf16x8*)(&sB[bu][(wc * NF * 16 + f * 16 + l15) * 64 + kk * 32 + l4 * 8]);
#pragma unroll
      for (int mf = 0; mf < MF; ++mf)
#pragma unroll
        for (int nf = 0; nf < NF; ++nf)
          acc[mf][nf] =
              __builtin_amdgcn_mfma_f32_16x16x32_bf16(af[mf], bfr[nf], acc[mf][nf], 0, 0, 0);
    }
  };

  const int nk = K / 64;
  if (DBUF) {
    stage(0, 0);
    for (int t = 0; t < nk; ++t) {
      const int cur = t & 1;
      __syncthreads();                     // stage(t) landed; buf cur^1 free
      if (t + 1 < nk) stage(cur ^ 1, (t + 1) * 64);
      compute(cur);                        // overlaps in-flight stage(t+1)
    }
  } else {
    for (int t = 0; t < nk; ++t) {
      stage(0, t * 64);
      __syncthreads();
      compute(0);
      __syncthreads();
    }
  }

#pragma unroll
  for (int mf = 0; mf < MF; ++mf) {
#pragma unroll
    for (int nf = 0; nf < NF; ++nf) {
      int col = n0 + wc * NF * 16 + nf * 16 + l15;
      float bv = bias[col];
#pragma unroll
      for (int j = 0; j < 4; ++j) {
        int row = m0 + wr * MF * 16 + mf * 16 + l4 * 4 + j;
        size_t o = (size_t)row * N + col;
        float v = acc[mf][nf][j] + bv;
        if (EPI == 0) {
          ((__hip_bfloat16*)outp)[o] = __float2bfloat16(v);
        } else if (EPI == 1) {
          ((float*)outp)[o] = v + resid[o];
        } else {
          float a = 0.7978845608028654f * (v + 0.044715f * v * v * v);
          a = fminf(fmaxf(a, -15.f), 15.f);
          float e = __expf(2.f * a);
          float th = (e - 1.f) / (e + 1.f);
          ((__hip_bfloat16*)outp)[o] = __float2bfloat16(0.5f * v * (1.f + th));
        }
      }
    }
  }
}

// ===============  Flash attention: 32x32 MFMA, in-register softmax  ================
// grid (S/128, B*H). 4 waves x 32 q-rows. KB=64, K/V double-buffered + XOR swizzle.
// Swapped QK^T: S^T = mfma_32x32x16(K_frag, Q_frag) -> lane owns one q-col (q=lane&31),
// 32 kv-scores split across lane+-32. Softmax lane-local; P packed via v_cvt_pk_bf16
// + permlane32_swap directly into PV A-fragments (no LDS P round-trip).
// Row-sums via ones-MFMA into accL (same row layout as acc -> no epilogue broadcast).
__global__ __launch_bounds__(256) void attn_kernel(
    const __hip_bfloat16* __restrict__ qkv, const __hip_bfloat16* __restrict__ vT,
    __hip_bfloat16* __restrict__ out) {
  __shared__ alignas(16) __hip_bfloat16 sK[2][64 * 64];   // [kv][dh], swizzled
  __shared__ alignas(16) __hip_bfloat16 sV[2][64 * 64];   // [dh][kv], swizzled
  __shared__ float sBr[4][32];                            // per-wave q-broadcast (rescale)
  const int tid = threadIdx.x, lane = tid & 63, wave = tid >> 6;
  const int l31 = lane & 31, hi = lane >> 5;
  const int bh = blockIdx.y, b = bh >> 4, h = bh & 15;
  const int q0 = blockIdx.x * 128;
  const int rsw = (l31 & 7) << 3;

  // Q as B-operand: lane holds Q[q = l31][d = ks*16 + hi*8 + jj]
  bf16x8 qf[4];
  {
    int qr = q0 + wave * 32 + l31;
    const size_t qbase = ((size_t)(b * S_ + qr)) * (3 * D_) + h * DH_;
#pragma unroll
    for (int ks = 0; ks < 4; ++ks)
      qf[ks] = *(const bf16x8*)(qkv + qbase + ks * 16 + hi * 8);
  }

  bf16x8 onesb;
#pragma unroll
  for (int i = 0; i < 8; ++i) onesb[i] = (__bf16)1.0f;

  f32x16 acc0, acc1, accL;  // D[q][dh] (+ row-sum); col = l31, rows = q(reg)
#pragma unroll
  for (int r = 0; r < 16; ++r) { acc0[r] = 0.f; acc1[r] = 0.f; accL[r] = 0.f; }
  float mrun = -1e30f;   // per-lane, for q = l31

  const __hip_bfloat16* kg = qkv + (size_t)b * S_ * (3 * D_) + D_ + h * DH_;
  const __hip_bfloat16* vg = vT + (size_t)bh * DH_ * S_;

  auto stage = [&](int bu, int kv0) {
#pragma unroll
    for (int it = 0; it < 2; ++it) {
      int idx = it * 256 + tid;          // 0..511
      int r = idx >> 3;                  // 0..63
      int c = (idx & 7) * 8;             // 0..56
      int cs = c ^ ((r & 7) << 3);       // inverse-swizzled source column
      g2lds16(kg + (size_t)(kv0 + r) * (3 * D_) + cs, (void*)(&sK[bu][idx * 8]));
      g2lds16(vg + (size_t)r * S_ + kv0 + cs, (void*)(&sV[bu][idx * 8]));
    }
  };

  stage(0, 0);
  const float k2 = 0.125f * 1.44269504f;  // scale * log2(e)
  const int NT = S_ / 64;

  for (int t = 0; t < NT; ++t) {
    const int cur = t & 1;
    __syncthreads();                       // drains our stage loads; guards buf reuse
    if (t + 1 < NT) stage(cur ^ 1, (t + 1) * 64);

    // ---- QK^T (swapped, 32x32x16): sf{0,1} = S^T[kv-block][q=l31] ----
    f32x16 sf0, sf1;
#pragma unroll
    for (int r = 0; r < 16; ++r) { sf0[r] = 0.f; sf1[r] = 0.f; }
    __builtin_amdgcn_s_setprio(1);
#pragma unroll
    for (int ks = 0; ks < 4; ++ks) {
      int colsw = (ks * 16 + hi * 8) ^ rsw;
      bf16x8 kf0 = *(const bf16x8*)(&sK[cur][l31 * 64 + colsw]);
      bf16x8 kf1 = *(const bf16x8*)(&sK[cur][(32 + l31) * 64 + colsw]);
      sf0 = __builtin_amdgcn_mfma_f32_32x32x16_bf16(kf0, qf[ks], sf0, 0, 0, 0);
      sf1 = __builtin_amdgcn_mfma_f32_32x32x16_bf16(kf1, qf[ks], sf1, 0, 0, 0);
    }
    __builtin_amdgcn_s_setprio(0);

    // ---- lane-local max (max3 tree) + defer-max gate (THR=8, log2 domain) ----
    float pm = fmaxf(rmax16(sf0), rmax16(sf1)) * k2;
    if (!__all(pm - mrun <= 8.0f)) {
      float mf = fmaxf(pm, __shfl_xor(pm, 32));
      float mn = fmaxf(mrun, mf);
      float corrl = exp2f(mrun - mn);
      mrun = mn;
      sBr[wave][l31] = corrl;            // lanes l31 & l31+32 write same value
#pragma unroll
      for (int r = 0; r < 16; ++r) {
        float cr = sBr[wave][(r & 3) + 8 * (r >> 2) + 4 * hi];
        acc0[r] *= cr;
        acc1[r] *= cr;
        accL[r] *= cr;
      }
    }

    // ---- P = exp2(S*k2 - m), pack to bf16, permlane into PV A-fragments ----
    bf16x8 pa[4];
#pragma unroll
    for (int kb = 0; kb < 2; ++kb) {
      const f32x16 s16 = kb ? sf1 : sf0;
#pragma unroll
      for (int ksb = 0; ksb < 2; ++ksb) {
        float p0 = exp2f(s16[8 * ksb + 0] * k2 - mrun);
        float p1 = exp2f(s16[8 * ksb + 1] * k2 - mrun);
        float p2 = exp2f(s16[8 * ksb + 2] * k2 - mrun);
        float p3 = exp2f(s16[8 * ksb + 3] * k2 - mrun);
        float p4 = exp2f(s16[8 * ksb + 4] * k2 - mrun);
        float p5 = exp2f(s16[8 * ksb + 5] * k2 - mrun);
        float p6 = exp2f(s16[8 * ksb + 6] * k2 - mrun);
        float p7 = exp2f(s16[8 * ksb + 7] * k2 - mrun);
        unsigned wa = pkbf16(p0, p1), wb = pkbf16(p2, p3);
        unsigned wc = pkbf16(p4, p5), wd = pkbf16(p6, p7);
        auto r1 = __builtin_amdgcn_permlane32_swap(wa, wc, false, false);
        auto r2 = __builtin_amdgcn_permlane32_swap(wb, wd, false, false);
        union { unsigned u[4]; bf16x8 v; } w;
        w.u[0] = r1[0]; w.u[1] = r2[0]; w.u[2] = r1[1]; w.u[3] = r2[1];
        pa[kb * 2 + ksb] = w.v;
      }
    }

    // ---- PV: acc[q][dh] += P_frag x V^T_frag;  accL += P_frag x ones ----
    __builtin_amdgcn_s_setprio(1);
#pragma unroll
    for (int ksg = 0; ksg < 4; ++ksg) {
      int colsw = (ksg * 16 + hi * 8) ^ rsw;
      bf16x8 vf0 = *(const bf16x8*)(&sV[cur][l31 * 64 + colsw]);
      bf16x8 vf1 = *(const bf16x8*)(&sV[cur][(32 + l31) * 64 + colsw]);
      acc0 = __builtin_amdgcn_mfma_f32_32x32x16_bf16(pa[ksg], vf0, acc0, 0, 0, 0);
      acc1 = __builtin_amdgcn_mfma_f32_32x32x16_bf16(pa[ksg], vf1, acc1, 0, 0, 0);
      accL = __builtin_amdgcn_mfma_f32_32x32x16_bf16(pa[ksg], onesb, accL, 0, 0, 0);
    }
    __builtin_amdgcn_s_setprio(0);
  }

  // ---- epilogue: inv = 1/accL[r] (same row layout as acc -> no broadcast) ----
#pragma unroll
  for (int r = 0; r < 16; ++r) {
    int qrow = (r & 3) + 8 * (r >> 2) + 4 * hi;
    float ir = 1.0f / accL[r];
    size_t obase = ((size_t)(b * S_ + q0 + wave * 32 + qrow)) * D_ + h * DH_ + l31;
    out[obase] = __float2bfloat16(acc0[r] * ir);
    out[obase + 32] = __float2bfloat16(acc1[r] * ir);
  }
}

// ====================================================================================
extern "C" void kernel_launch(void* const* d_in, const int* in_sizes, int n_in,
                              void* d_out, int out_size, void* d_ws, size_t ws_size,
                              hipStream_t stream) {
  const float* x = (const float*)d_in[0];
  const float* ln1_g = (const float*)d_in[1];
  const float* ln1_b = (const float*)d_in[2];
  const float* Wqkv = (const float*)d_in[3];
  const float* bqkv = (const float*)d_in[4];
  const float* Wo = (const float*)d_in[5];
  const float* bo = (const float*)d_in[6];
  const float* ln2_g = (const float*)d_in[7];
  const float* ln2_b = (const float*)d_in[8];
  const float* W1 = (const float*)d_in[9];
  const float* b1 = (const float*)d_in[10];
  const float* W2 = (const float*)d_in[11];
  const float* b2 = (const float*)d_in[12];
  float* out = (float*)d_out;

  char* ws = (char*)d_ws;
  size_t off = 0;
  auto alloc = [&](size_t bytes) {
    void* p = ws + off;
    off += (bytes + 255) & ~(size_t)255;
    return p;
  };
  __hip_bfloat16* WqkvT = (__hip_bfloat16*)alloc((size_t)3 * D_ * D_ * 2);
  __hip_bfloat16* WoT = (__hip_bfloat16*)alloc((size_t)D_ * D_ * 2);
  __hip_bfloat16* W1T = (__hip_bfloat16*)alloc((size_t)FF_ * D_ * 2);
  __hip_bfloat16* W2T = (__hip_bfloat16*)alloc((size_t)D_ * FF_ * 2);
  __hip_bfloat16* h = (__hip_bfloat16*)alloc((size_t)MR_ * D_ * 2);
  __hip_bfloat16* qkv = (__hip_bfloat16*)alloc((size_t)MR_ * FF_ * 2);  // shared w/ ff
  __hip_bfloat16* ff = qkv;
  __hip_bfloat16* vT = (__hip_bfloat16*)alloc((size_t)B_ * H_ * DH_ * S_ * 2);
  __hip_bfloat16* attn_out = (__hip_bfloat16*)alloc((size_t)MR_ * D_ * 2);

  dim3 tb(32, 8);
  // 1. weight prep
  transpose_cvt<<<dim3(3 * D_ / 32, D_ / 32), tb, 0, stream>>>(Wqkv, WqkvT, D_, 3 * D_);
  transpose_cvt<<<dim3(D_ / 32, D_ / 32), tb, 0, stream>>>(Wo, WoT, D_, D_);
  transpose_cvt<<<dim3(FF_ / 32, D_ / 32), tb, 0, stream>>>(W1, W1T, D_, FF_);
  transpose_cvt<<<dim3(D_ / 32, FF_ / 32), tb, 0, stream>>>(W2, W2T, FF_, D_);
  // 2. LN1
  ln_kernel<<<MR_, 256, 0, stream>>>(x, ln1_g, ln1_b, h);
  // 3. QKV gemm (128x128 tile, 2x2 waves, single-buf: 3 blocks/CU)
  gemm_bt<0, 128, 128, 2, 2, false><<<dim3(3 * D_ / 128, MR_ / 128), 256, 0, stream>>>(
      h, WqkvT, bqkv, nullptr, qkv, MR_, 3 * D_, D_);
  // 4. V transpose
  transpose_v<<<dim3(S_ / 32, DH_ / 32, B_ * H_), tb, 0, stream>>>(qkv, vT);
  // 5. attention
  attn_kernel<<<dim3(S_ / 128, B_ * H_), 256, 0, stream>>>(qkv, vT, attn_out);
  // 6. Wo gemm + residual -> d_out. N=1024, grid 512 (2/CU) -> DBUF overlap
  gemm_bt<1, 128, 64, 4, 1, true><<<dim3(D_ / 64, MR_ / 128), 256, 0, stream>>>(
      attn_out, WoT, bo, x, out, MR_, D_, D_);
  // 7. LN2 (reuse h)
  ln_kernel<<<MR_, 256, 0, stream>>>(out, ln2_g, ln2_b, h);
  // 8. W1 gemm + gelu (128x128 tile, single-buf: 4 blocks/CU)
  gemm_bt<2, 128, 128, 2, 2, false><<<dim3(FF_ / 128, MR_ / 128), 256, 0, stream>>>(
      h, W1T, b1, nullptr, ff, MR_, FF_, D_);
  // 9. W2 gemm + residual(d_out) -> d_out. N=1024, K=4096 -> DBUF overlap
  gemm_bt<1, 128, 64, 4, 1, true><<<dim3(D_ / 64, MR_ / 128), 256, 0, stream>>>(
      ff, W2T, b2, out, out, MR_, D_, FF_);
}

// Round 7
// 263.307 us; speedup vs baseline: 1.5061x; 1.0678x over previous
//
#include <hip/hip_runtime.h>
#include <hip/hip_bf16.h>
#include <cstdint>

#define D_ 1024
#define H_ 16
#define DH_ 64
#define FF_ 4096
#define B_ 2
#define S_ 2048
#define MR_ (B_ * S_)   // 4096 rows

typedef __bf16 bf16x8 __attribute__((ext_vector_type(8)));
typedef __bf16 bf16x4 __attribute__((ext_vector_type(4)));
typedef float f32x4 __attribute__((ext_vector_type(4)));
typedef float f32x16 __attribute__((ext_vector_type(16)));

// ---- async global->LDS, 16B per lane (linear dest in lane order) ----
__device__ __forceinline__ void g2lds16(const void* g, void* l) {
  __builtin_amdgcn_global_load_lds(
      (__attribute__((address_space(1))) void*)(uintptr_t)g,
      (__attribute__((address_space(3))) void*)(uint32_t)(uintptr_t)l,
      16, 0, 0);
}

// pack two f32 -> one u32 holding 2 bf16 (lo, hi)
__device__ __forceinline__ unsigned pkbf16(float lo, float hi) {
  unsigned r;
  asm("v_cvt_pk_bf16_f32 %0, %1, %2" : "=v"(r) : "v"(lo), "v"(hi));
  return r;
}

__device__ __forceinline__ float max3f(float a, float b, float c) {
  float d;
  asm("v_max3_f32 %0, %1, %2, %3" : "=v"(d) : "v"(a), "v"(b), "v"(c));
  return d;
}

__device__ __forceinline__ float rmax16(const f32x16& v) {
  float t0 = max3f(v[0], v[1], v[2]);
  float t1 = max3f(v[3], v[4], v[5]);
  float t2 = max3f(v[6], v[7], v[8]);
  float t3 = max3f(v[9], v[10], v[11]);
  float t4 = max3f(v[12], v[13], v[14]);
  return fmaxf(max3f(t0, t1, t2), max3f(t3, t4, v[15]));
}

// =====================  weight transpose + fp32->bf16  =====================
__global__ __launch_bounds__(256) void transpose_cvt(
    const float* __restrict__ W, __hip_bfloat16* __restrict__ Wt, int K, int N) {
  __shared__ float t[32][33];
  int bx = blockIdx.x * 32;  // n
  int by = blockIdx.y * 32;  // k
  int tx = threadIdx.x, ty = threadIdx.y;  // (32,8)
#pragma unroll
  for (int i = 0; i < 4; ++i)
    t[ty + 8 * i][tx] = W[(size_t)(by + ty + 8 * i) * N + bx + tx];
  __syncthreads();
#pragma unroll
  for (int i = 0; i < 4; ++i)
    Wt[(size_t)(bx + ty + 8 * i) * K + by + tx] = __float2bfloat16(t[tx][ty + 8 * i]);
}

// ==============  V slice transpose: qkv[b,s, 2D + h*64 + d] -> vT[b,h,d,s]  ==========
__global__ __launch_bounds__(256) void transpose_v(
    const __hip_bfloat16* __restrict__ qkv, __hip_bfloat16* __restrict__ vT) {
  __shared__ __hip_bfloat16 t[32][33];
  int bh = blockIdx.z, b = bh >> 4, h = bh & 15;
  int s0 = blockIdx.x * 32, d0 = blockIdx.y * 32;
  int tx = threadIdx.x, ty = threadIdx.y;
#pragma unroll
  for (int i = 0; i < 4; ++i)
    t[ty + 8 * i][tx] =
        qkv[(size_t)(b * S_ + s0 + ty + 8 * i) * (3 * D_) + 2 * D_ + h * DH_ + d0 + tx];
  __syncthreads();
#pragma unroll
  for (int i = 0; i < 4; ++i)
    vT[(size_t)(bh * DH_ + d0 + ty + 8 * i) * S_ + s0 + tx] = t[tx][ty + 8 * i];
}

// ==========================  LayerNorm (fp32 in, bf16 out)  ========================
__global__ __launch_bounds__(256) void ln_kernel(
    const float* __restrict__ x, const float* __restrict__ g,
    const float* __restrict__ b, __hip_bfloat16* __restrict__ out) {
  int row = blockIdx.x;
  const float4* xr = (const float4*)(x + (size_t)row * D_);
  float4 v = xr[threadIdx.x];
  float s = v.x + v.y + v.z + v.w;
  float ss = v.x * v.x + v.y * v.y + v.z * v.z + v.w * v.w;
#pragma unroll
  for (int m = 1; m < 64; m <<= 1) {
    s += __shfl_xor(s, m);
    ss += __shfl_xor(ss, m);
  }
  __shared__ float rs[4], rss[4];
  int wave = threadIdx.x >> 6, lane = threadIdx.x & 63;
  if (lane == 0) { rs[wave] = s; rss[wave] = ss; }
  __syncthreads();
  s = rs[0] + rs[1] + rs[2] + rs[3];
  ss = rss[0] + rss[1] + rss[2] + rss[3];
  float mean = s * (1.0f / D_);
  float var = ss * (1.0f / D_) - mean * mean;
  float inv = rsqrtf(var + 1e-5f);
  int c = threadIdx.x * 4;
  float4 gv = ((const float4*)g)[threadIdx.x];
  float4 bv = ((const float4*)b)[threadIdx.x];
  __hip_bfloat16* o = out + (size_t)row * D_ + c;
  o[0] = __float2bfloat16((v.x - mean) * inv * gv.x + bv.x);
  o[1] = __float2bfloat16((v.y - mean) * inv * gv.y + bv.y);
  o[2] = __float2bfloat16((v.z - mean) * inv * gv.z + bv.z);
  o[3] = __float2bfloat16((v.w - mean) * inv * gv.w + bv.w);
}

// ============  GEMM3: C[M,N] = A[M,K]*Bt[N,K]^T + bias (+epilogue)  =================
// BM=256, BN=128, BK=64. 8 waves (4M x 2N), each 64x64 (MF=NF=4).
// 3-buffer LDS ring: stage K-tile j+2 while computing j -> counted vmcnt(6), never a
// full drain in the main loop. Raw s_barrier (no __syncthreads vmcnt(0) drain).
// XOR bank swizzle both-sides: LDS[r][c] = G[r][c ^ ((r&7)<<3)]; reads apply same XOR.
// EPI 0: bf16 +bias;  1: f32 +bias+resid;  2: bf16 +bias+gelu.
template <int EPI>
__global__ __launch_bounds__(512) void gemm3(
    const __hip_bfloat16* __restrict__ A, const __hip_bfloat16* __restrict__ Bt,
    const float* __restrict__ bias, const float* __restrict__ resid,
    void* __restrict__ outp, int M, int N, int K) {
  __shared__ alignas(16) __hip_bfloat16 sA[3][256 * 64];
  __shared__ alignas(16) __hip_bfloat16 sB[3][128 * 64];
  const int tid = threadIdx.x;                 // 0..511
  const int lane = tid & 63, wave = tid >> 6;  // 8 waves
  const int l15 = lane & 15, l4 = lane >> 4;
  const int wr = wave >> 1, wc = wave & 1;     // 4 x 2 wave grid, 64x64 each
  const int csw = (l15 & 7) << 3;              // read-side XOR swizzle

  // XCD-aware bijective block swizzle (all grids divisible by 8)
  const int gx = gridDim.x;
  int nwg = gx * gridDim.y;
  int flat = blockIdx.y * gx + blockIdx.x;
  int cpx = nwg >> 3;
  int swz = (flat & 7) * cpx + (flat >> 3);
  const int m0 = (swz / gx) * 256, n0 = (swz % gx) * 128;

  f32x4 z = {0.f, 0.f, 0.f, 0.f};
  f32x4 acc[4][4];
#pragma unroll
  for (int i = 0; i < 4; ++i)
#pragma unroll
    for (int j = 0; j < 4; ++j) acc[i][j] = z;

  auto stageA = [&](int bu, int kt) {   // 4 VMEM instr / thread
#pragma unroll
    for (int it = 0; it < 4; ++it) {
      int idx = it * 512 + tid;
      int r = idx >> 3, c = (idx & 7) * 8;
      int cs = c ^ ((r & 7) << 3);
      g2lds16(A + (size_t)(m0 + r) * K + kt + cs, (void*)(&sA[bu][idx * 8]));
    }
  };
  auto stageB = [&](int bu, int kt) {   // 2 VMEM instr / thread
#pragma unroll
    for (int it = 0; it < 2; ++it) {
      int idx = it * 512 + tid;
      int r = idx >> 3, c = (idx & 7) * 8;
      int cs = c ^ ((r & 7) << 3);
      g2lds16(Bt + (size_t)(n0 + r) * K + kt + cs, (void*)(&sB[bu][idx * 8]));
    }
  };

  const int nk = K / 64;
  // prologue: stage tiles 0 and 1 (12 VMEM in flight) -> wait tile 0 (vmcnt 6)
  stageA(0, 0);
  stageB(0, 0);
  stageA(1, 64);
  stageB(1, 64);
  asm volatile("s_waitcnt vmcnt(6)" ::: "memory");
  __builtin_amdgcn_s_barrier();

  int bu = 0, bu2 = 2;  // compute buf, prefetch buf (=(j+2)%3)
  for (int j = 0; j < nk; ++j) {
    const bool pf = (j + 2) < nk;
    if (pf) stageA(bu2, (j + 2) * 64);   // issue early

    __builtin_amdgcn_s_setprio(1);
#pragma unroll
    for (int kk = 0; kk < 2; ++kk) {
      bf16x8 bfr[4];
      int col = (kk * 32 + l4 * 8) ^ csw;
#pragma unroll
      for (int nf = 0; nf < 4; ++nf)
        bfr[nf] = *(const bf16x8*)(&sB[bu][(wc * 64 + nf * 16 + l15) * 64 + col]);
#pragma unroll
      for (int mf = 0; mf < 4; ++mf) {
        bf16x8 af = *(const bf16x8*)(&sA[bu][(wr * 64 + mf * 16 + l15) * 64 + col]);
#pragma unroll
        for (int nf = 0; nf < 4; ++nf)
          acc[mf][nf] =
              __builtin_amdgcn_mfma_f32_16x16x32_bf16(af, bfr[nf], acc[mf][nf], 0, 0, 0);
      }
    }
    __builtin_amdgcn_s_setprio(0);

    if (pf) stageB(bu2, (j + 2) * 64);

    if (pf)
      asm volatile("s_waitcnt vmcnt(6)" ::: "memory");  // drain tile j+1 only
    else
      asm volatile("s_waitcnt vmcnt(0)" ::: "memory");  // tail
    __builtin_amdgcn_s_barrier();
    asm volatile("" ::: "memory");
    bu = (bu == 2) ? 0 : bu + 1;
    bu2 = (bu2 == 2) ? 0 : bu2 + 1;
  }

  // epilogue
#pragma unroll
  for (int mf = 0; mf < 4; ++mf) {
#pragma unroll
    for (int nf = 0; nf < 4; ++nf) {
      int col = n0 + wc * 64 + nf * 16 + l15;
      float bv = bias[col];
#pragma unroll
      for (int j = 0; j < 4; ++j) {
        int row = m0 + wr * 64 + mf * 16 + l4 * 4 + j;
        size_t o = (size_t)row * N + col;
        float v = acc[mf][nf][j] + bv;
        if (EPI == 0) {
          ((__hip_bfloat16*)outp)[o] = __float2bfloat16(v);
        } else if (EPI == 1) {
          ((float*)outp)[o] = v + resid[o];
        } else {
          float a = 0.7978845608028654f * (v + 0.044715f * v * v * v);
          a = fminf(fmaxf(a, -15.f), 15.f);
          float e = __expf(2.f * a);
          float th = (e - 1.f) / (e + 1.f);
          ((__hip_bfloat16*)outp)[o] = __float2bfloat16(0.5f * v * (1.f + th));
        }
      }
    }
  }
}

// ===============  Flash attention: 32x32 MFMA, in-register softmax  ================
__global__ __launch_bounds__(256) void attn_kernel(
    const __hip_bfloat16* __restrict__ qkv, const __hip_bfloat16* __restrict__ vT,
    __hip_bfloat16* __restrict__ out) {
  __shared__ alignas(16) __hip_bfloat16 sK[2][64 * 64];   // [kv][dh], swizzled
  __shared__ alignas(16) __hip_bfloat16 sV[2][64 * 64];   // [dh][kv], swizzled
  __shared__ float sBr[4][32];                            // per-wave q-broadcast (rescale)
  const int tid = threadIdx.x, lane = tid & 63, wave = tid >> 6;
  const int l31 = lane & 31, hi = lane >> 5;
  const int bh = blockIdx.y, b = bh >> 4, h = bh & 15;
  const int q0 = blockIdx.x * 128;
  const int rsw = (l31 & 7) << 3;

  bf16x8 qf[4];
  {
    int qr = q0 + wave * 32 + l31;
    const size_t qbase = ((size_t)(b * S_ + qr)) * (3 * D_) + h * DH_;
#pragma unroll
    for (int ks = 0; ks < 4; ++ks)
      qf[ks] = *(const bf16x8*)(qkv + qbase + ks * 16 + hi * 8);
  }

  bf16x8 onesb;
#pragma unroll
  for (int i = 0; i < 8; ++i) onesb[i] = (__bf16)1.0f;

  f32x16 acc0, acc1, accL;
#pragma unroll
  for (int r = 0; r < 16; ++r) { acc0[r] = 0.f; acc1[r] = 0.f; accL[r] = 0.f; }
  float mrun = -1e30f;

  const __hip_bfloat16* kg = qkv + (size_t)b * S_ * (3 * D_) + D_ + h * DH_;
  const __hip_bfloat16* vg = vT + (size_t)bh * DH_ * S_;

  auto stage = [&](int bu, int kv0) {
#pragma unroll
    for (int it = 0; it < 2; ++it) {
      int idx = it * 256 + tid;
      int r = idx >> 3;
      int c = (idx & 7) * 8;
      int cs = c ^ ((r & 7) << 3);
      g2lds16(kg + (size_t)(kv0 + r) * (3 * D_) + cs, (void*)(&sK[bu][idx * 8]));
      g2lds16(vg + (size_t)r * S_ + kv0 + cs, (void*)(&sV[bu][idx * 8]));
    }
  };

  stage(0, 0);
  const float k2 = 0.125f * 1.44269504f;
  const int NT = S_ / 64;

  for (int t = 0; t < NT; ++t) {
    const int cur = t & 1;
    __syncthreads();
    if (t + 1 < NT) stage(cur ^ 1, (t + 1) * 64);

    f32x16 sf0, sf1;
#pragma unroll
    for (int r = 0; r < 16; ++r) { sf0[r] = 0.f; sf1[r] = 0.f; }
    __builtin_amdgcn_s_setprio(1);
#pragma unroll
    for (int ks = 0; ks < 4; ++ks) {
      int colsw = (ks * 16 + hi * 8) ^ rsw;
      bf16x8 kf0 = *(const bf16x8*)(&sK[cur][l31 * 64 + colsw]);
      bf16x8 kf1 = *(const bf16x8*)(&sK[cur][(32 + l31) * 64 + colsw]);
      sf0 = __builtin_amdgcn_mfma_f32_32x32x16_bf16(kf0, qf[ks], sf0, 0, 0, 0);
      sf1 = __builtin_amdgcn_mfma_f32_32x32x16_bf16(kf1, qf[ks], sf1, 0, 0, 0);
    }
    __builtin_amdgcn_s_setprio(0);

    float pm = fmaxf(rmax16(sf0), rmax16(sf1)) * k2;
    if (!__all(pm - mrun <= 8.0f)) {
      float mf = fmaxf(pm, __shfl_xor(pm, 32));
      float mn = fmaxf(mrun, mf);
      float corrl = exp2f(mrun - mn);
      mrun = mn;
      sBr[wave][l31] = corrl;
#pragma unroll
      for (int r = 0; r < 16; ++r) {
        float cr = sBr[wave][(r & 3) + 8 * (r >> 2) + 4 * hi];
        acc0[r] *= cr;
        acc1[r] *= cr;
        accL[r] *= cr;
      }
    }

    bf16x8 pa[4];
#pragma unroll
    for (int kb = 0; kb < 2; ++kb) {
      const f32x16 s16 = kb ? sf1 : sf0;
#pragma unroll
      for (int ksb = 0; ksb < 2; ++ksb) {
        float p0 = exp2f(s16[8 * ksb + 0] * k2 - mrun);
        float p1 = exp2f(s16[8 * ksb + 1] * k2 - mrun);
        float p2 = exp2f(s16[8 * ksb + 2] * k2 - mrun);
        float p3 = exp2f(s16[8 * ksb + 3] * k2 - mrun);
        float p4 = exp2f(s16[8 * ksb + 4] * k2 - mrun);
        float p5 = exp2f(s16[8 * ksb + 5] * k2 - mrun);
        float p6 = exp2f(s16[8 * ksb + 6] * k2 - mrun);
        float p7 = exp2f(s16[8 * ksb + 7] * k2 - mrun);
        unsigned wa = pkbf16(p0, p1), wb = pkbf16(p2, p3);
        unsigned wc = pkbf16(p4, p5), wd = pkbf16(p6, p7);
        auto r1 = __builtin_amdgcn_permlane32_swap(wa, wc, false, false);
        auto r2 = __builtin_amdgcn_permlane32_swap(wb, wd, false, false);
        union { unsigned u[4]; bf16x8 v; } w;
        w.u[0] = r1[0]; w.u[1] = r2[0]; w.u[2] = r1[1]; w.u[3] = r2[1];
        pa[kb * 2 + ksb] = w.v;
      }
    }

    __builtin_amdgcn_s_setprio(1);
#pragma unroll
    for (int ksg = 0; ksg < 4; ++ksg) {
      int colsw = (ksg * 16 + hi * 8) ^ rsw;
      bf16x8 vf0 = *(const bf16x8*)(&sV[cur][l31 * 64 + colsw]);
      bf16x8 vf1 = *(const bf16x8*)(&sV[cur][(32 + l31) * 64 + colsw]);
      acc0 = __builtin_amdgcn_mfma_f32_32x32x16_bf16(pa[ksg], vf0, acc0, 0, 0, 0);
      acc1 = __builtin_amdgcn_mfma_f32_32x32x16_bf16(pa[ksg], vf1, acc1, 0, 0, 0);
      accL = __builtin_amdgcn_mfma_f32_32x32x16_bf16(pa[ksg], onesb, accL, 0, 0, 0);
    }
    __builtin_amdgcn_s_setprio(0);
  }

#pragma unroll
  for (int r = 0; r < 16; ++r) {
    int qrow = (r & 3) + 8 * (r >> 2) + 4 * hi;
    float ir = 1.0f / accL[r];
    size_t obase = ((size_t)(b * S_ + q0 + wave * 32 + qrow)) * D_ + h * DH_ + l31;
    out[obase] = __float2bfloat16(acc0[r] * ir);
    out[obase + 32] = __float2bfloat16(acc1[r] * ir);
  }
}

// ====================================================================================
extern "C" void kernel_launch(void* const* d_in, const int* in_sizes, int n_in,
                              void* d_out, int out_size, void* d_ws, size_t ws_size,
                              hipStream_t stream) {
  const float* x = (const float*)d_in[0];
  const float* ln1_g = (const float*)d_in[1];
  const float* ln1_b = (const float*)d_in[2];
  const float* Wqkv = (const float*)d_in[3];
  const float* bqkv = (const float*)d_in[4];
  const float* Wo = (const float*)d_in[5];
  const float* bo = (const float*)d_in[6];
  const float* ln2_g = (const float*)d_in[7];
  const float* ln2_b = (const float*)d_in[8];
  const float* W1 = (const float*)d_in[9];
  const float* b1 = (const float*)d_in[10];
  const float* W2 = (const float*)d_in[11];
  const float* b2 = (const float*)d_in[12];
  float* out = (float*)d_out;

  char* ws = (char*)d_ws;
  size_t off = 0;
  auto alloc = [&](size_t bytes) {
    void* p = ws + off;
    off += (bytes + 255) & ~(size_t)255;
    return p;
  };
  __hip_bfloat16* WqkvT = (__hip_bfloat16*)alloc((size_t)3 * D_ * D_ * 2);
  __hip_bfloat16* WoT = (__hip_bfloat16*)alloc((size_t)D_ * D_ * 2);
  __hip_bfloat16* W1T = (__hip_bfloat16*)alloc((size_t)FF_ * D_ * 2);
  __hip_bfloat16* W2T = (__hip_bfloat16*)alloc((size_t)D_ * FF_ * 2);
  __hip_bfloat16* h = (__hip_bfloat16*)alloc((size_t)MR_ * D_ * 2);
  __hip_bfloat16* qkv = (__hip_bfloat16*)alloc((size_t)MR_ * FF_ * 2);  // shared w/ ff
  __hip_bfloat16* ff = qkv;
  __hip_bfloat16* vT = (__hip_bfloat16*)alloc((size_t)B_ * H_ * DH_ * S_ * 2);
  __hip_bfloat16* attn_out = (__hip_bfloat16*)alloc((size_t)MR_ * D_ * 2);

  dim3 tb(32, 8);
  // 1. weight prep
  transpose_cvt<<<dim3(3 * D_ / 32, D_ / 32), tb, 0, stream>>>(Wqkv, WqkvT, D_, 3 * D_);
  transpose_cvt<<<dim3(D_ / 32, D_ / 32), tb, 0, stream>>>(Wo, WoT, D_, D_);
  transpose_cvt<<<dim3(FF_ / 32, D_ / 32), tb, 0, stream>>>(W1, W1T, D_, FF_);
  transpose_cvt<<<dim3(D_ / 32, FF_ / 32), tb, 0, stream>>>(W2, W2T, FF_, D_);
  // 2. LN1
  ln_kernel<<<MR_, 256, 0, stream>>>(x, ln1_g, ln1_b, h);
  // 3. QKV gemm: 256x128 tile -> grid (24,16) = 384 blocks
  gemm3<0><<<dim3(3 * D_ / 128, MR_ / 256), 512, 0, stream>>>(
      h, WqkvT, bqkv, nullptr, qkv, MR_, 3 * D_, D_);
  // 4. V transpose
  transpose_v<<<dim3(S_ / 32, DH_ / 32, B_ * H_), tb, 0, stream>>>(qkv, vT);
  // 5. attention
  attn_kernel<<<dim3(S_ / 128, B_ * H_), 256, 0, stream>>>(qkv, vT, attn_out);
  // 6. Wo gemm + residual -> d_out (fp32): grid (8,16) = 128 blocks
  gemm3<1><<<dim3(D_ / 128, MR_ / 256), 512, 0, stream>>>(
      attn_out, WoT, bo, x, out, MR_, D_, D_);
  // 7. LN2 (reuse h)
  ln_kernel<<<MR_, 256, 0, stream>>>(out, ln2_g, ln2_b, h);
  // 8. W1 gemm + gelu: grid (32,16) = 512 blocks
  gemm3<2><<<dim3(FF_ / 128, MR_ / 256), 512, 0, stream>>>(
      h, W1T, b1, nullptr, ff, MR_, FF_, D_);
  // 9. W2 gemm + residual(d_out) -> d_out: grid (8,16) = 128 blocks
  gemm3<1><<<dim3(D_ / 128, MR_ / 256), 512, 0, stream>>>(
      ff, W2T, b2, out, out, MR_, D_, FF_);
}

// Round 9
// 239.732 us; speedup vs baseline: 1.6542x; 1.0983x over previous
//
#include <hip/hip_runtime.h>
#include <hip/hip_bf16.h>
#include <cstdint>

#define D_ 1024
#define H_ 16
#define DH_ 64
#define FF_ 4096
#define B_ 2
#define S_ 2048
#define MR_ (B_ * S_)   // 4096 rows

typedef __bf16 bf16x8 __attribute__((ext_vector_type(8)));
typedef __bf16 bf16x4 __attribute__((ext_vector_type(4)));
typedef float f32x4 __attribute__((ext_vector_type(4)));
typedef float f32x16 __attribute__((ext_vector_type(16)));

// ---- async global->LDS, 16B per lane (linear dest in lane order) ----
__device__ __forceinline__ void g2lds16(const void* g, void* l) {
  __builtin_amdgcn_global_load_lds(
      (__attribute__((address_space(1))) void*)(uintptr_t)g,
      (__attribute__((address_space(3))) void*)(uint32_t)(uintptr_t)l,
      16, 0, 0);
}

// pack two f32 -> one u32 holding 2 bf16 (lo, hi)
__device__ __forceinline__ unsigned pkbf16(float lo, float hi) {
  unsigned r;
  asm("v_cvt_pk_bf16_f32 %0, %1, %2" : "=v"(r) : "v"(lo), "v"(hi));
  return r;
}

__device__ __forceinline__ float max3f(float a, float b, float c) {
  float d;
  asm("v_max3_f32 %0, %1, %2, %3" : "=v"(d) : "v"(a), "v"(b), "v"(c));
  return d;
}

__device__ __forceinline__ float rmax16(const f32x16& v) {
  float t0 = max3f(v[0], v[1], v[2]);
  float t1 = max3f(v[3], v[4], v[5]);
  float t2 = max3f(v[6], v[7], v[8]);
  float t3 = max3f(v[9], v[10], v[11]);
  float t4 = max3f(v[12], v[13], v[14]);
  return fmaxf(max3f(t0, t1, t2), max3f(t3, t4, v[15]));
}

// =====================  weight transpose + fp32->bf16  =====================
__global__ __launch_bounds__(256) void transpose_cvt(
    const float* __restrict__ W, __hip_bfloat16* __restrict__ Wt, int K, int N) {
  __shared__ float t[32][33];
  int bx = blockIdx.x * 32;  // n
  int by = blockIdx.y * 32;  // k
  int tx = threadIdx.x, ty = threadIdx.y;  // (32,8)
#pragma unroll
  for (int i = 0; i < 4; ++i)
    t[ty + 8 * i][tx] = W[(size_t)(by + ty + 8 * i) * N + bx + tx];
  __syncthreads();
#pragma unroll
  for (int i = 0; i < 4; ++i)
    Wt[(size_t)(bx + ty + 8 * i) * K + by + tx] = __float2bfloat16(t[tx][ty + 8 * i]);
}

// ==============  V slice transpose: qkv[b,s, 2D + h*64 + d] -> vT[b,h,d,s]  ==========
__global__ __launch_bounds__(256) void transpose_v(
    const __hip_bfloat16* __restrict__ qkv, __hip_bfloat16* __restrict__ vT) {
  __shared__ __hip_bfloat16 t[32][33];
  int bh = blockIdx.z, b = bh >> 4, h = bh & 15;
  int s0 = blockIdx.x * 32, d0 = blockIdx.y * 32;
  int tx = threadIdx.x, ty = threadIdx.y;
#pragma unroll
  for (int i = 0; i < 4; ++i)
    t[ty + 8 * i][tx] =
        qkv[(size_t)(b * S_ + s0 + ty + 8 * i) * (3 * D_) + 2 * D_ + h * DH_ + d0 + tx];
  __syncthreads();
#pragma unroll
  for (int i = 0; i < 4; ++i)
    vT[(size_t)(bh * DH_ + d0 + ty + 8 * i) * S_ + s0 + tx] = t[tx][ty + 8 * i];
}

// ==========================  LayerNorm (fp32 in, bf16 out)  ========================
__global__ __launch_bounds__(256) void ln_kernel(
    const float* __restrict__ x, const float* __restrict__ g,
    const float* __restrict__ b, __hip_bfloat16* __restrict__ out) {
  int row = blockIdx.x;
  const float4* xr = (const float4*)(x + (size_t)row * D_);
  float4 v = xr[threadIdx.x];
  float s = v.x + v.y + v.z + v.w;
  float ss = v.x * v.x + v.y * v.y + v.z * v.z + v.w * v.w;
#pragma unroll
  for (int m = 1; m < 64; m <<= 1) {
    s += __shfl_xor(s, m);
    ss += __shfl_xor(ss, m);
  }
  __shared__ float rs[4], rss[4];
  int wave = threadIdx.x >> 6, lane = threadIdx.x & 63;
  if (lane == 0) { rs[wave] = s; rss[wave] = ss; }
  __syncthreads();
  s = rs[0] + rs[1] + rs[2] + rs[3];
  ss = rss[0] + rss[1] + rss[2] + rss[3];
  float mean = s * (1.0f / D_);
  float var = ss * (1.0f / D_) - mean * mean;
  float inv = rsqrtf(var + 1e-5f);
  int c = threadIdx.x * 4;
  float4 gv = ((const float4*)g)[threadIdx.x];
  float4 bv = ((const float4*)b)[threadIdx.x];
  __hip_bfloat16* o = out + (size_t)row * D_ + c;
  o[0] = __float2bfloat16((v.x - mean) * inv * gv.x + bv.x);
  o[1] = __float2bfloat16((v.y - mean) * inv * gv.y + bv.y);
  o[2] = __float2bfloat16((v.z - mean) * inv * gv.z + bv.z);
  o[3] = __float2bfloat16((v.w - mean) * inv * gv.w + bv.w);
}

// ============  GEMM3: C[M,N] = A[M,K]*Bt[N,K]^T + bias (+epilogue)  =================
// BN=128 fixed; BM/wave-grid templated. 8 waves (WM x WN), per-wave (BM/WM)x(BN/WN).
// 3-buffer LDS ring: stage K-tile j+2 while computing j -> counted vmcnt(loads/tile).
// RACE GUARD (rule #18/#21): before signaling each barrier, s_waitcnt lgkmcnt(0) +
// sched_barrier(0) force this wave's ds_reads to have landed in registers -- without
// it hipcc can sink the consuming MFMAs (register-only) past the barrier, and the
// next iteration's global_load_lds overwrites the LDS region a pending ds_read is
// still targeting (intermittent corruption, caught by post-timing revalidation R8).
// EPI 0: bf16 +bias;  1: f32 +bias+resid;  2: bf16 +bias+gelu.
template <int EPI, int BM, int WM, int WN>
__global__ __launch_bounds__(512) void gemm3(
    const __hip_bfloat16* __restrict__ A, const __hip_bfloat16* __restrict__ Bt,
    const float* __restrict__ bias, const float* __restrict__ resid,
    void* __restrict__ outp, int M, int N, int K) {
  constexpr int BN = 128;
  constexpr int MF = BM / (WM * 16);
  constexpr int NF = BN / (WN * 16);
  constexpr int VMN = BM / 64 + 2;   // VMEM instrs per K-tile per thread
  __shared__ alignas(16) __hip_bfloat16 sA[3][BM * 64];
  __shared__ alignas(16) __hip_bfloat16 sB[3][BN * 64];
  const int tid = threadIdx.x;                 // 0..511
  const int lane = tid & 63, wave = tid >> 6;  // 8 waves
  const int l15 = lane & 15, l4 = lane >> 4;
  const int wr = wave / WN, wc = wave % WN;
  const int csw = (l15 & 7) << 3;              // read-side XOR swizzle

  // XCD-aware bijective block swizzle (all grids divisible by 8)
  const int gx = gridDim.x;
  int nwg = gx * gridDim.y;
  int flat = blockIdx.y * gx + blockIdx.x;
  int cpx = nwg >> 3;
  int swz = (flat & 7) * cpx + (flat >> 3);
  const int m0 = (swz / gx) * BM, n0 = (swz % gx) * BN;

  f32x4 z = {0.f, 0.f, 0.f, 0.f};
  f32x4 acc[MF][NF];
#pragma unroll
  for (int i = 0; i < MF; ++i)
#pragma unroll
    for (int j = 0; j < NF; ++j) acc[i][j] = z;

  auto stageA = [&](int bu, int kt) {   // BM/64 VMEM instr / thread
#pragma unroll
    for (int it = 0; it < BM / 64; ++it) {
      int idx = it * 512 + tid;
      int r = idx >> 3, c = (idx & 7) * 8;
      int cs = c ^ ((r & 7) << 3);
      g2lds16(A + (size_t)(m0 + r) * K + kt + cs, (void*)(&sA[bu][idx * 8]));
    }
  };
  auto stageB = [&](int bu, int kt) {   // 2 VMEM instr / thread
#pragma unroll
    for (int it = 0; it < 2; ++it) {
      int idx = it * 512 + tid;
      int r = idx >> 3, c = (idx & 7) * 8;
      int cs = c ^ ((r & 7) << 3);
      g2lds16(Bt + (size_t)(n0 + r) * K + kt + cs, (void*)(&sB[bu][idx * 8]));
    }
  };

  const int nk = K / 64;
  // prologue: stage tiles 0 and 1 -> wait tile 0 (vmcnt = one tile's loads)
  stageA(0, 0);
  stageB(0, 0);
  stageA(1, 64);
  stageB(1, 64);
  if constexpr (VMN == 6)
    asm volatile("s_waitcnt vmcnt(6)" ::: "memory");
  else
    asm volatile("s_waitcnt vmcnt(4)" ::: "memory");
  __builtin_amdgcn_s_barrier();

  int bu = 0, bu2 = 2;  // compute buf, prefetch buf (=(j+2)%3)
  for (int j = 0; j < nk; ++j) {
    const bool pf = (j + 2) < nk;
    if (pf) stageA(bu2, (j + 2) * 64);   // issue early

    __builtin_amdgcn_s_setprio(1);
#pragma unroll
    for (int kk = 0; kk < 2; ++kk) {
      bf16x8 bfr[NF];
      int col = (kk * 32 + l4 * 8) ^ csw;
#pragma unroll
      for (int nf = 0; nf < NF; ++nf)
        bfr[nf] = *(const bf16x8*)(&sB[bu][(wc * NF * 16 + nf * 16 + l15) * 64 + col]);
#pragma unroll
      for (int mf = 0; mf < MF; ++mf) {
        bf16x8 af = *(const bf16x8*)(&sA[bu][(wr * MF * 16 + mf * 16 + l15) * 64 + col]);
#pragma unroll
        for (int nf = 0; nf < NF; ++nf)
          acc[mf][nf] =
              __builtin_amdgcn_mfma_f32_16x16x32_bf16(af, bfr[nf], acc[mf][nf], 0, 0, 0);
      }
    }
    __builtin_amdgcn_s_setprio(0);

    if (pf) stageB(bu2, (j + 2) * 64);

    // RACE GUARD: this wave's ds_reads must have landed before it signals the
    // barrier (next iteration's load_lds overwrites the buffer they target).
    asm volatile("s_waitcnt lgkmcnt(0)" ::: "memory");
    __builtin_amdgcn_sched_barrier(0);

    if (pf) {
      if constexpr (VMN == 6)
        asm volatile("s_waitcnt vmcnt(6)" ::: "memory");  // drain tile j+1 only
      else
        asm volatile("s_waitcnt vmcnt(4)" ::: "memory");
    } else {
      asm volatile("s_waitcnt vmcnt(0)" ::: "memory");    // tail
    }
    __builtin_amdgcn_s_barrier();
    asm volatile("" ::: "memory");
    bu = (bu == 2) ? 0 : bu + 1;
    bu2 = (bu2 == 2) ? 0 : bu2 + 1;
  }

  // epilogue
#pragma unroll
  for (int mf = 0; mf < MF; ++mf) {
#pragma unroll
    for (int nf = 0; nf < NF; ++nf) {
      int col = n0 + wc * NF * 16 + nf * 16 + l15;
      float bv = bias[col];
#pragma unroll
      for (int j = 0; j < 4; ++j) {
        int row = m0 + wr * MF * 16 + mf * 16 + l4 * 4 + j;
        size_t o = (size_t)row * N + col;
        float v = acc[mf][nf][j] + bv;
        if (EPI == 0) {
          ((__hip_bfloat16*)outp)[o] = __float2bfloat16(v);
        } else if (EPI == 1) {
          ((float*)outp)[o] = v + resid[o];
        } else {
          float a = 0.7978845608028654f * (v + 0.044715f * v * v * v);
          a = fminf(fmaxf(a, -15.f), 15.f);
          float e = __expf(2.f * a);
          float th = (e - 1.f) / (e + 1.f);
          ((__hip_bfloat16*)outp)[o] = __float2bfloat16(0.5f * v * (1.f + th));
        }
      }
    }
  }
}

// ===============  Flash attention: 32x32 MFMA, in-register softmax  ================
// Q pre-scaled by k2 = 0.125*log2(e) at load -> scores already in log2 units.
__global__ __launch_bounds__(256) void attn_kernel(
    const __hip_bfloat16* __restrict__ qkv, const __hip_bfloat16* __restrict__ vT,
    __hip_bfloat16* __restrict__ out) {
  __shared__ alignas(16) __hip_bfloat16 sK[2][64 * 64];   // [kv][dh], swizzled
  __shared__ alignas(16) __hip_bfloat16 sV[2][64 * 64];   // [dh][kv], swizzled
  __shared__ float sBr[4][32];                            // per-wave q-broadcast (rescale)
  const int tid = threadIdx.x, lane = tid & 63, wave = tid >> 6;
  const int l31 = lane & 31, hi = lane >> 5;
  const int bh = blockIdx.y, b = bh >> 4, h = bh & 15;
  const int q0 = blockIdx.x * 128;
  const int rsw = (l31 & 7) << 3;
  const float k2 = 0.125f * 1.44269504f;

  // Q as B-operand, pre-scaled by k2 (scores come out of MFMA in log2 units)
  bf16x8 qf[4];
  {
    int qr = q0 + wave * 32 + l31;
    const size_t qbase = ((size_t)(b * S_ + qr)) * (3 * D_) + h * DH_;
#pragma unroll
    for (int ks = 0; ks < 4; ++ks) {
      bf16x8 q = *(const bf16x8*)(qkv + qbase + ks * 16 + hi * 8);
#pragma unroll
      for (int i = 0; i < 8; ++i) q[i] = (__bf16)((float)q[i] * k2);
      qf[ks] = q;
    }
  }

  bf16x8 onesb;
#pragma unroll
  for (int i = 0; i < 8; ++i) onesb[i] = (__bf16)1.0f;

  f32x16 acc0, acc1, accL;
#pragma unroll
  for (int r = 0; r < 16; ++r) { acc0[r] = 0.f; acc1[r] = 0.f; accL[r] = 0.f; }
  float mrun = -1e30f;

  const __hip_bfloat16* kg = qkv + (size_t)b * S_ * (3 * D_) + D_ + h * DH_;
  const __hip_bfloat16* vg = vT + (size_t)bh * DH_ * S_;

  auto stage = [&](int bu, int kv0) {
#pragma unroll
    for (int it = 0; it < 2; ++it) {
      int idx = it * 256 + tid;
      int r = idx >> 3;
      int c = (idx & 7) * 8;
      int cs = c ^ ((r & 7) << 3);
      g2lds16(kg + (size_t)(kv0 + r) * (3 * D_) + cs, (void*)(&sK[bu][idx * 8]));
      g2lds16(vg + (size_t)r * S_ + kv0 + cs, (void*)(&sV[bu][idx * 8]));
    }
  };

  stage(0, 0);
  const int NT = S_ / 64;

  for (int t = 0; t < NT; ++t) {
    const int cur = t & 1;
    __syncthreads();
    if (t + 1 < NT) stage(cur ^ 1, (t + 1) * 64);

    f32x16 sf0, sf1;
#pragma unroll
    for (int r = 0; r < 16; ++r) { sf0[r] = 0.f; sf1[r] = 0.f; }
    __builtin_amdgcn_s_setprio(1);
#pragma unroll
    for (int ks = 0; ks < 4; ++ks) {
      int colsw = (ks * 16 + hi * 8) ^ rsw;
      bf16x8 kf0 = *(const bf16x8*)(&sK[cur][l31 * 64 + colsw]);
      bf16x8 kf1 = *(const bf16x8*)(&sK[cur][(32 + l31) * 64 + colsw]);
      sf0 = __builtin_amdgcn_mfma_f32_32x32x16_bf16(kf0, qf[ks], sf0, 0, 0, 0);
      sf1 = __builtin_amdgcn_mfma_f32_32x32x16_bf16(kf1, qf[ks], sf1, 0, 0, 0);
    }
    __builtin_amdgcn_s_setprio(0);

    float pm = fmaxf(rmax16(sf0), rmax16(sf1));   // already log2 units
    if (!__all(pm - mrun <= 8.0f)) {
      float mf = fmaxf(pm, __shfl_xor(pm, 32));
      float mn = fmaxf(mrun, mf);
      float corrl = exp2f(mrun - mn);
      mrun = mn;
      sBr[wave][l31] = corrl;
#pragma unroll
      for (int r = 0; r < 16; ++r) {
        float cr = sBr[wave][(r & 3) + 8 * (r >> 2) + 4 * hi];
        acc0[r] *= cr;
        acc1[r] *= cr;
        accL[r] *= cr;
      }
    }

    bf16x8 pa[4];
#pragma unroll
    for (int kb = 0; kb < 2; ++kb) {
      const f32x16 s16 = kb ? sf1 : sf0;
#pragma unroll
      for (int ksb = 0; ksb < 2; ++ksb) {
        float p0 = exp2f(s16[8 * ksb + 0] - mrun);
        float p1 = exp2f(s16[8 * ksb + 1] - mrun);
        float p2 = exp2f(s16[8 * ksb + 2] - mrun);
        float p3 = exp2f(s16[8 * ksb + 3] - mrun);
        float p4 = exp2f(s16[8 * ksb + 4] - mrun);
        float p5 = exp2f(s16[8 * ksb + 5] - mrun);
        float p6 = exp2f(s16[8 * ksb + 6] - mrun);
        float p7 = exp2f(s16[8 * ksb + 7] - mrun);
        unsigned wa = pkbf16(p0, p1), wb = pkbf16(p2, p3);
        unsigned wc = pkbf16(p4, p5), wd = pkbf16(p6, p7);
        auto r1 = __builtin_amdgcn_permlane32_swap(wa, wc, false, false);
        auto r2 = __builtin_amdgcn_permlane32_swap(wb, wd, false, false);
        union { unsigned u[4]; bf16x8 v; } w;
        w.u[0] = r1[0]; w.u[1] = r2[0]; w.u[2] = r1[1]; w.u[3] = r2[1];
        pa[kb * 2 + ksb] = w.v;
      }
    }

    __builtin_amdgcn_s_setprio(1);
#pragma unroll
    for (int ksg = 0; ksg < 4; ++ksg) {
      int colsw = (ksg * 16 + hi * 8) ^ rsw;
      bf16x8 vf0 = *(const bf16x8*)(&sV[cur][l31 * 64 + colsw]);
      bf16x8 vf1 = *(const bf16x8*)(&sV[cur][(32 + l31) * 64 + colsw]);
      acc0 = __builtin_amdgcn_mfma_f32_32x32x16_bf16(pa[ksg], vf0, acc0, 0, 0, 0);
      acc1 = __builtin_amdgcn_mfma_f32_32x32x16_bf16(pa[ksg], vf1, acc1, 0, 0, 0);
      accL = __builtin_amdgcn_mfma_f32_32x32x16_bf16(pa[ksg], onesb, accL, 0, 0, 0);
    }
    __builtin_amdgcn_s_setprio(0);
  }

#pragma unroll
  for (int r = 0; r < 16; ++r) {
    int qrow = (r & 3) + 8 * (r >> 2) + 4 * hi;
    float ir = 1.0f / accL[r];
    size_t obase = ((size_t)(b * S_ + q0 + wave * 32 + qrow)) * D_ + h * DH_ + l31;
    out[obase] = __float2bfloat16(acc0[r] * ir);
    out[obase + 32] = __float2bfloat16(acc1[r] * ir);
  }
}

// ====================================================================================
extern "C" void kernel_launch(void* const* d_in, const int* in_sizes, int n_in,
                              void* d_out, int out_size, void* d_ws, size_t ws_size,
                              hipStream_t stream) {
  const float* x = (const float*)d_in[0];
  const float* ln1_g = (const float*)d_in[1];
  const float* ln1_b = (const float*)d_in[2];
  const float* Wqkv = (const float*)d_in[3];
  const float* bqkv = (const float*)d_in[4];
  const float* Wo = (const float*)d_in[5];
  const float* bo = (const float*)d_in[6];
  const float* ln2_g = (const float*)d_in[7];
  const float* ln2_b = (const float*)d_in[8];
  const float* W1 = (const float*)d_in[9];
  const float* b1 = (const float*)d_in[10];
  const float* W2 = (const float*)d_in[11];
  const float* b2 = (const float*)d_in[12];
  float* out = (float*)d_out;

  char* ws = (char*)d_ws;
  size_t off = 0;
  auto alloc = [&](size_t bytes) {
    void* p = ws + off;
    off += (bytes + 255) & ~(size_t)255;
    return p;
  };
  __hip_bfloat16* WqkvT = (__hip_bfloat16*)alloc((size_t)3 * D_ * D_ * 2);
  __hip_bfloat16* WoT = (__hip_bfloat16*)alloc((size_t)D_ * D_ * 2);
  __hip_bfloat16* W1T = (__hip_bfloat16*)alloc((size_t)FF_ * D_ * 2);
  __hip_bfloat16* W2T = (__hip_bfloat16*)alloc((size_t)D_ * FF_ * 2);
  __hip_bfloat16* h = (__hip_bfloat16*)alloc((size_t)MR_ * D_ * 2);
  __hip_bfloat16* qkv = (__hip_bfloat16*)alloc((size_t)MR_ * FF_ * 2);  // shared w/ ff
  __hip_bfloat16* ff = qkv;
  __hip_bfloat16* vT = (__hip_bfloat16*)alloc((size_t)B_ * H_ * DH_ * S_ * 2);
  __hip_bfloat16* attn_out = (__hip_bfloat16*)alloc((size_t)MR_ * D_ * 2);

  dim3 tb(32, 8);
  // 1. weight prep
  transpose_cvt<<<dim3(3 * D_ / 32, D_ / 32), tb, 0, stream>>>(Wqkv, WqkvT, D_, 3 * D_);
  transpose_cvt<<<dim3(D_ / 32, D_ / 32), tb, 0, stream>>>(Wo, WoT, D_, D_);
  transpose_cvt<<<dim3(FF_ / 32, D_ / 32), tb, 0, stream>>>(W1, W1T, D_, FF_);
  transpose_cvt<<<dim3(D_ / 32, FF_ / 32), tb, 0, stream>>>(W2, W2T, FF_, D_);
  // 2. LN1
  ln_kernel<<<MR_, 256, 0, stream>>>(x, ln1_g, ln1_b, h);
  // 3. QKV gemm: 128x128 tile -> grid (24,32) = 768 = 3/CU exact
  gemm3<0, 128, 2, 4><<<dim3(3 * D_ / 128, MR_ / 128), 512, 0, stream>>>(
      h, WqkvT, bqkv, nullptr, qkv, MR_, 3 * D_, D_);
  // 4. V transpose
  transpose_v<<<dim3(S_ / 32, DH_ / 32, B_ * H_), tb, 0, stream>>>(qkv, vT);
  // 5. attention
  attn_kernel<<<dim3(S_ / 128, B_ * H_), 256, 0, stream>>>(qkv, vT, attn_out);
  // 6. Wo gemm + residual -> d_out (fp32): 128x128 -> grid (8,32) = 256 = 1/CU exact
  gemm3<1, 128, 2, 4><<<dim3(D_ / 128, MR_ / 128), 512, 0, stream>>>(
      attn_out, WoT, bo, x, out, MR_, D_, D_);
  // 7. LN2 (reuse h)
  ln_kernel<<<MR_, 256, 0, stream>>>(out, ln2_g, ln2_b, h);
  // 8. W1 gemm + gelu: 256x128 -> grid (32,16) = 512 = 2/CU exact
  gemm3<2, 256, 4, 2><<<dim3(FF_ / 128, MR_ / 256), 512, 0, stream>>>(
      h, W1T, b1, nullptr, ff, MR_, FF_, D_);
  // 9. W2 gemm + residual(d_out) -> d_out: 128x128 -> grid (8,32) = 256 = 1/CU exact
  gemm3<1, 128, 2, 4><<<dim3(D_ / 128, MR_ / 128), 512, 0, stream>>>(
      ff, W2T, b2, out, out, MR_, D_, FF_);
}